// Round 9
// baseline (657.934 us; speedup 1.0000x reference)
//
#include <hip/hip_runtime.h>
#include <hip/hip_bf16.h>
#include <math.h>

#define V_   32000
#define L_   4
#define H_   4
#define D_   256
#define DF_  1024
#define B_   2
#define T_   2048
#define DH_  64
#define NTOK (B_*T_)   // 4096

typedef __attribute__((ext_vector_type(8))) short bf16x8;
typedef __attribute__((ext_vector_type(4))) float f32x4;
typedef unsigned short u16;

#define GLOAD16(gsrc, ldst) \
  __builtin_amdgcn_global_load_lds((const __attribute__((address_space(1))) void*)(gsrc), \
                                   (__attribute__((address_space(3))) void*)(ldst), 16, 0, 0)

__device__ __forceinline__ u16 f2bf(float f) {
    unsigned int u = __builtin_bit_cast(unsigned int, f);
    u = (u + 0x7fff + ((u >> 16) & 1)) >> 16;   // RNE
    return (u16)u;
}

__device__ __forceinline__ int xcd_swizzle(int orig, int nwg) {
    return ((nwg & 7) == 0) ? ((orig & 7) * (nwg >> 3) + (orig >> 3)) : orig;
}

// ================= prep: weight transposes f32[K,N] -> bf16[N,K], 64k x 32n tiles =====
__global__ __launch_bounds__(256) void prep_kernel(
    const float* __restrict__ Wq, const float* __restrict__ Wk,
    const float* __restrict__ Wv, const float* __restrict__ Wo,
    const float* __restrict__ W1, const float* __restrict__ W2,
    const float* __restrict__ hW,
    u16* __restrict__ WqkvT, u16* __restrict__ WoT,
    u16* __restrict__ W1T, u16* __restrict__ W2T, u16* __restrict__ hWT)
{
    int b = blockIdx.x;
    const float* src; u16* dst; int K, N, k0, n0;
    if (b < 512) {
        int m = b >> 5, t = b & 31;
        int wt = m & 3, l = m >> 2;
        K = 256; N = 256;
        src = (wt == 0 ? Wq : wt == 1 ? Wk : wt == 2 ? Wv : Wo) + (size_t)l * 65536;
        dst = (wt < 3) ? WqkvT + (size_t)l * 196608 + (size_t)wt * 65536
                       : WoT + (size_t)l * 65536;
        k0 = (t >> 3) * 64; n0 = (t & 7) * 32;
    } else if (b < 1024) {
        int bb = b - 512; int l = bb >> 7, t = bb & 127;
        K = 256; N = 1024;
        src = W1 + (size_t)l * 262144; dst = W1T + (size_t)l * 262144;
        k0 = (t >> 5) * 64; n0 = (t & 31) * 32;
    } else if (b < 1536) {
        int bb = b - 1024; int l = bb >> 7, t = bb & 127;
        K = 1024; N = 256;
        src = W2 + (size_t)l * 262144; dst = W2T + (size_t)l * 262144;
        k0 = (t >> 3) * 64; n0 = (t & 7) * 32;
    } else {
        int bb = b - 1536;
        K = 256; N = 32000;
        src = hW; dst = hWT;
        k0 = (bb / 1000) * 64; n0 = (bb % 1000) * 32;
    }
    __shared__ float tile[64][33];
    int tid = threadIdx.x;
    int tc = tid & 31, tr = tid >> 5;
    #pragma unroll
    for (int i = 0; i < 8; i++)
        tile[tr + i*8][tc] = src[(size_t)(k0 + tr + i*8) * N + n0 + tc];
    __syncthreads();
    int kc = tid & 63, nr = tid >> 6;
    #pragma unroll
    for (int i = 0; i < 8; i++)
        dst[(size_t)(n0 + nr + i*4) * K + k0 + kc] = f2bf(tile[kc][nr + i*4]);
}

// ================= embed + LN1(l0) + QKV(l0): 256 blocks x 256t, 16 rows/block =========
__global__ __launch_bounds__(256) void embed_qkv_kernel(
    const int* __restrict__ idx, const float* __restrict__ tok, const float* __restrict__ pos,
    const float* __restrict__ g, const float* __restrict__ bta,
    const u16* __restrict__ WqkvT0,
    const float* __restrict__ bq, const float* __restrict__ bk, const float* __restrict__ bv,
    float* __restrict__ x, u16* __restrict__ qkv)
{
    __shared__ u16 Bs[2][256*64];
    __shared__ u16 hS[16][264];

    int tid = threadIdx.x;
    int lane = tid & 63, w = tid >> 6;
    int lr = lane & 15, lg = lane >> 4;
    int bid = xcd_swizzle(blockIdx.x, 256);
    int row0 = bid * 16;

    {
        int grow = tid >> 4;
        int gcol = (tid & 15) * 16;
        int n = row0 + grow;
        int t = n & (T_ - 1);
        int id = idx[n];
        float vv[16];
        #pragma unroll
        for (int i = 0; i < 4; i++) {
            float4 a = *(const float4*)(tok + (size_t)id * D_ + gcol + i * 4);
            float4 b = *(const float4*)(pos + (size_t)t * D_ + gcol + i * 4);
            vv[i*4+0] = a.x + b.x; vv[i*4+1] = a.y + b.y;
            vv[i*4+2] = a.z + b.z; vv[i*4+3] = a.w + b.w;
        }
        float s = 0.f, q = 0.f;
        #pragma unroll
        for (int i = 0; i < 16; i++) { s += vv[i]; q += vv[i]*vv[i]; }
        #pragma unroll
        for (int o = 1; o <= 8; o <<= 1) { s += __shfl_xor(s, o); q += __shfl_xor(q, o); }
        float mu = s * (1.0f / D_);
        float var = q * (1.0f / D_) - mu * mu;
        float ri = rsqrtf(var + 1e-5f);
        #pragma unroll
        for (int i = 0; i < 16; i++) {
            x[(size_t)n * D_ + gcol + i] = vv[i];
            hS[grow][gcol + i] = f2bf((vv[i] - mu) * ri * g[gcol + i] + bta[gcol + i]);
        }
    }

    auto stageQ = [&](int buf, int u) {
        const u16* BT = WqkvT0 + (size_t)(u >> 2) * 65536;
        int k0 = (u & 3) * 64;
        #pragma unroll
        for (int i = 0; i < 8; i++) {
            int o16 = tid + i * 256;
            int r = o16 >> 3;
            int sw = ((o16 & 7) << 4) ^ ((r & 7) << 4);
            GLOAD16(BT + (size_t)r * 256 + k0 + (sw >> 1), &Bs[buf][o16 * 8]);
        }
    };
    auto afH = [&](int t, int ks) -> bf16x8 {
        return *(const bf16x8*)(&hS[lr][(t * 128 + ks * 64 + lg * 16) >> 1]);
    };
    auto bfr = [&](int buf, int ni, int ks) -> bf16x8 {
        int rr = w * 64 + ni * 16 + lr;
        return *(const bf16x8*)(&Bs[buf][rr * 64 + (((ks * 64 + lg * 16) ^ ((rr & 7) << 4)) >> 1)]);
    };

    stageQ(0, 0);
    f32x4 acc[4] = {};
    for (int u = 0; u < 12; u++) {
        __syncthreads();
        if (u + 1 < 12) stageQ((u + 1) & 1, u + 1);
        int t = u & 3;
        #pragma unroll
        for (int ks = 0; ks < 2; ks++) {
            bf16x8 a = afH(t, ks);
            __builtin_amdgcn_s_setprio(1);
            #pragma unroll
            for (int ni = 0; ni < 4; ni++)
                acc[ni] = __builtin_amdgcn_mfma_f32_16x16x32_bf16(a, bfr(u & 1, ni, ks), acc[ni], 0, 0, 0);
            __builtin_amdgcn_s_setprio(0);
        }
        if (t == 3) {
            int sel = u >> 2;
            const float* bp = sel == 0 ? bq : sel == 1 ? bk : bv;
            #pragma unroll
            for (int ni = 0; ni < 4; ni++) {
                #pragma unroll
                for (int j = 0; j < 4; j++) {
                    int row = row0 + lg * 4 + j;
                    int cc = w * 64 + ni * 16 + lr;
                    float v = acc[ni][j] + bp[cc];
                    int bb = row >> 11, tt = row & (T_ - 1);
                    int hh = cc >> 6, dh = cc & 63;
                    qkv[(size_t)sel * NTOK * D_ +
                        ((((size_t)bb * H_ + hh) * T_) + tt) * DH_ + dh] = f2bf(v);
                }
                acc[ni] = (f32x4){0.f, 0.f, 0.f, 0.f};
            }
        }
    }
}

// ======= fused Wo+res+LN2 + FF1+GELU: 256 blocks x 256t, 16 rows/block, LDS 78.6KB =====
__global__ __launch_bounds__(256) void woff1_kernel(
    const u16* __restrict__ ybuf,
    const u16* __restrict__ WoT, const float* __restrict__ bo,
    const u16* __restrict__ W1T, const float* __restrict__ b1,
    const float* __restrict__ ln2g, const float* __restrict__ ln2b,
    float* __restrict__ x, u16* __restrict__ ff)
{
    __shared__ u16 Bs[2][256*64];     // 64 KB
    __shared__ u16 As[2][16*64];      // 4 KB
    __shared__ u16 hS[16][264];       // 8.25 KB
    __shared__ float sred[4][16], qred[4][16];

    int tid = threadIdx.x;
    int lane = tid & 63, w = tid >> 6;
    int lr = lane & 15, lg = lane >> 4;
    int bid = xcd_swizzle(blockIdx.x, 256);
    int row0 = bid * 16;

    auto stageB = [&](int buf, const u16* BT, int k0) {
        #pragma unroll
        for (int i = 0; i < 8; i++) {
            int o16 = tid + i * 256;
            int r = o16 >> 3;
            int sw = ((o16 & 7) << 4) ^ ((r & 7) << 4);
            GLOAD16(BT + (size_t)r * 256 + k0 + (sw >> 1), &Bs[buf][o16 * 8]);
        }
    };
    auto stageA = [&](int buf, int k0) {
        if (tid < 128) {
            int r = tid >> 3;
            int sw = ((tid & 7) << 4) ^ ((r & 7) << 4);
            GLOAD16(ybuf + (size_t)(row0 + r) * 256 + k0 + (sw >> 1), &As[buf][tid * 8]);
        }
    };
    // stages: 0-3 Wo | 4-19 FF1 (4 col-chunks x 4 k-tiles)
    auto prefetch = [&](int u) {
        int buf = u & 1;
        if (u < 4)       { stageA(buf, u * 64); stageB(buf, WoT, u * 64); }
        else if (u < 20) { int v = u - 4; stageB(buf, W1T + (size_t)(v >> 2) * 65536, (v & 3) * 64); }
    };
    auto afA = [&](int buf, int ks) -> bf16x8 {
        return *(const bf16x8*)(&As[buf][lr * 64 + (((ks * 64 + lg * 16) ^ ((lr & 7) << 4)) >> 1)]);
    };
    auto afH = [&](int t, int ks) -> bf16x8 {
        return *(const bf16x8*)(&hS[lr][(t * 128 + ks * 64 + lg * 16) >> 1]);
    };
    auto bfr = [&](int buf, int ni, int ks) -> bf16x8 {
        int rr = w * 64 + ni * 16 + lr;
        return *(const bf16x8*)(&Bs[buf][rr * 64 + (((ks * 64 + lg * 16) ^ ((rr & 7) << 4)) >> 1)]);
    };

    prefetch(0);

    // ---- Phase A: Wo GEMM ----
    {
        f32x4 acc[4] = {};
        for (int u = 0; u < 4; u++) {
            __syncthreads();
            prefetch(u + 1);
            #pragma unroll
            for (int ks = 0; ks < 2; ks++) {
                bf16x8 a = afA(u & 1, ks);
                __builtin_amdgcn_s_setprio(1);
                #pragma unroll
                for (int ni = 0; ni < 4; ni++)
                    acc[ni] = __builtin_amdgcn_mfma_f32_16x16x32_bf16(a, bfr(u & 1, ni, ks), acc[ni], 0, 0, 0);
                __builtin_amdgcn_s_setprio(0);
            }
        }
        // epilogue: x' = acc + bo + x -> x, LN2 -> hS
        float vals[4][4];
        float rs[4] = {0,0,0,0}, rq[4] = {0,0,0,0};
        #pragma unroll
        for (int ni = 0; ni < 4; ni++)
            #pragma unroll
            for (int j = 0; j < 4; j++) {
                int row = row0 + lg * 4 + j;
                int col = w * 64 + ni * 16 + lr;
                float v = acc[ni][j] + bo[col] + x[(size_t)row * D_ + col];
                x[(size_t)row * D_ + col] = v;
                vals[ni][j] = v;
                rs[j] += v; rq[j] += v * v;
            }
        #pragma unroll
        for (int j = 0; j < 4; j++)
            #pragma unroll
            for (int o = 1; o <= 8; o <<= 1) { rs[j] += __shfl_xor(rs[j], o); rq[j] += __shfl_xor(rq[j], o); }
        if (lr == 0)
            #pragma unroll
            for (int j = 0; j < 4; j++) { sred[w][lg*4 + j] = rs[j]; qred[w][lg*4 + j] = rq[j]; }
        __syncthreads();
        #pragma unroll
        for (int j = 0; j < 4; j++) {
            int r = lg * 4 + j;
            float mu = (sred[0][r] + sred[1][r] + sred[2][r] + sred[3][r]) * (1.0f / D_);
            float var = (qred[0][r] + qred[1][r] + qred[2][r] + qred[3][r]) * (1.0f / D_) - mu * mu;
            float ri = rsqrtf(var + 1e-5f);
            #pragma unroll
            for (int ni = 0; ni < 4; ni++) {
                int col = w * 64 + ni * 16 + lr;
                hS[r][col] = f2bf((vals[ni][j] - mu) * ri * ln2g[col] + ln2b[col]);
            }
        }
    }

    // ---- Phase B: FF1 + GELU -> ff (HBM) ----
    {
        f32x4 acc[4] = {};
        for (int u = 4; u < 20; u++) {
            __syncthreads();
            prefetch(u + 1);
            int v = u - 4;
            int t = v & 3;
            #pragma unroll
            for (int ks = 0; ks < 2; ks++) {
                bf16x8 a = afH(t, ks);
                __builtin_amdgcn_s_setprio(1);
                #pragma unroll
                for (int ni = 0; ni < 4; ni++)
                    acc[ni] = __builtin_amdgcn_mfma_f32_16x16x32_bf16(a, bfr(u & 1, ni, ks), acc[ni], 0, 0, 0);
                __builtin_amdgcn_s_setprio(0);
            }
            if (t == 3) {
                int c = v >> 2;
                #pragma unroll
                for (int ni = 0; ni < 4; ni++) {
                    #pragma unroll
                    for (int j = 0; j < 4; j++) {
                        int row = row0 + lg * 4 + j;
                        int col = w * 64 + ni * 16 + lr;
                        float vv = acc[ni][j] + b1[c * 256 + col];
                        vv = 0.5f * vv * (1.0f + erff(vv * 0.70710678118f));
                        ff[(size_t)row * DF_ + c * 256 + col] = f2bf(vv);
                    }
                    acc[ni] = (f32x4){0.f, 0.f, 0.f, 0.f};
                }
            }
        }
    }
}

// ================= FF2 + residual + LN(next) + QKV(next): 256 blocks, 16 rows =========
template<bool LAST>
__global__ __launch_bounds__(256) void ff2qkv_kernel(
    const u16* __restrict__ ff, const u16* __restrict__ W2T, const float* __restrict__ b2,
    const float* __restrict__ lng, const float* __restrict__ lnb,
    const u16* __restrict__ WqkvT,
    const float* __restrict__ bq, const float* __restrict__ bk, const float* __restrict__ bv,
    float* __restrict__ x, u16* __restrict__ hout, u16* __restrict__ qkv)
{
    __shared__ u16 As[2][16*64];
    __shared__ u16 Bs[2][256*64];
    __shared__ u16 hS[16][264];
    __shared__ float sred[4][16], qred[4][16];

    int tid = threadIdx.x;
    int lane = tid & 63, w = tid >> 6;
    int lr = lane & 15, lg = lane >> 4;
    int bid = xcd_swizzle(blockIdx.x, 256);
    int row0 = bid * 16;

    auto stageB = [&](int buf, const u16* BT, int K, int k0) {
        #pragma unroll
        for (int i = 0; i < 8; i++) {
            int o16 = tid + i * 256;
            int r = o16 >> 3;
            int sw = ((o16 & 7) << 4) ^ ((r & 7) << 4);
            GLOAD16(BT + (size_t)r * K + k0 + (sw >> 1), &Bs[buf][o16 * 8]);
        }
    };
    auto stageA = [&](int buf, int k0) {
        if (tid < 128) {
            int r = tid >> 3;
            int sw = ((tid & 7) << 4) ^ ((r & 7) << 4);
            GLOAD16(ff + (size_t)(row0 + r) * DF_ + k0 + (sw >> 1), &As[buf][tid * 8]);
        }
    };
    auto prefetch = [&](int u) {
        if (u < 16) { stageA(u & 1, u * 64); stageB(u & 1, W2T, 1024, u * 64); }
        else if (!LAST && u < 28) {
            int v = u - 16;
            stageB(u & 1, WqkvT + (size_t)(v >> 2) * 65536, 256, (v & 3) * 64);
        }
    };
    auto afA = [&](int buf, int ks) -> bf16x8 {
        return *(const bf16x8*)(&As[buf][lr * 64 + (((ks * 64 + lg * 16) ^ ((lr & 7) << 4)) >> 1)]);
    };
    auto afH = [&](int t, int ks) -> bf16x8 {
        return *(const bf16x8*)(&hS[lr][(t * 128 + ks * 64 + lg * 16) >> 1]);
    };
    auto bfr = [&](int buf, int ni, int ks) -> bf16x8 {
        int rr = w * 64 + ni * 16 + lr;
        return *(const bf16x8*)(&Bs[buf][rr * 64 + (((ks * 64 + lg * 16) ^ ((rr & 7) << 4)) >> 1)]);
    };

    prefetch(0);
    f32x4 acc[4] = {};
    for (int u = 0; u < 16; u++) {
        __syncthreads();
        prefetch(u + 1);
        #pragma unroll
        for (int ks = 0; ks < 2; ks++) {
            bf16x8 a = afA(u & 1, ks);
            __builtin_amdgcn_s_setprio(1);
            #pragma unroll
            for (int ni = 0; ni < 4; ni++)
                acc[ni] = __builtin_amdgcn_mfma_f32_16x16x32_bf16(a, bfr(u & 1, ni, ks), acc[ni], 0, 0, 0);
            __builtin_amdgcn_s_setprio(0);
        }
    }

    {
        float vals[4][4];
        float rs[4] = {0,0,0,0}, rq[4] = {0,0,0,0};
        #pragma unroll
        for (int ni = 0; ni < 4; ni++)
            #pragma unroll
            for (int j = 0; j < 4; j++) {
                int row = row0 + lg * 4 + j;
                int col = w * 64 + ni * 16 + lr;
                float v = acc[ni][j] + b2[col] + x[(size_t)row * D_ + col];
                x[(size_t)row * D_ + col] = v;
                vals[ni][j] = v;
                rs[j] += v; rq[j] += v * v;
            }
        #pragma unroll
        for (int j = 0; j < 4; j++)
            #pragma unroll
            for (int o = 1; o <= 8; o <<= 1) { rs[j] += __shfl_xor(rs[j], o); rq[j] += __shfl_xor(rq[j], o); }
        if (lr == 0)
            #pragma unroll
            for (int j = 0; j < 4; j++) { sred[w][lg*4 + j] = rs[j]; qred[w][lg*4 + j] = rq[j]; }
        __syncthreads();
        #pragma unroll
        for (int j = 0; j < 4; j++) {
            int r = lg * 4 + j;
            float mu = (sred[0][r] + sred[1][r] + sred[2][r] + sred[3][r]) * (1.0f / D_);
            float var = (qred[0][r] + qred[1][r] + qred[2][r] + qred[3][r]) * (1.0f / D_) - mu * mu;
            float ri = rsqrtf(var + 1e-5f);
            #pragma unroll
            for (int ni = 0; ni < 4; ni++) {
                int col = w * 64 + ni * 16 + lr;
                float hv = (vals[ni][j] - mu) * ri * lng[col] + lnb[col];
                if (LAST) hout[(size_t)(row0 + r) * D_ + col] = f2bf(hv);
                else      hS[r][col] = f2bf(hv);
            }
        }
    }

    if constexpr (!LAST) {
        f32x4 accT[4] = {};
        for (int v = 0; v < 12; v++) {
            __syncthreads();
            prefetch(16 + v + 1);
            int t = v & 3;
            #pragma unroll
            for (int ks = 0; ks < 2; ks++) {
                bf16x8 a = afH(t, ks);
                __builtin_amdgcn_s_setprio(1);
                #pragma unroll
                for (int ni = 0; ni < 4; ni++)
                    accT[ni] = __builtin_amdgcn_mfma_f32_16x16x32_bf16(a, bfr(v & 1, ni, ks), accT[ni], 0, 0, 0);
                __builtin_amdgcn_s_setprio(0);
            }
            if (t == 3) {
                int sel = v >> 2;
                const float* bp = sel == 0 ? bq : sel == 1 ? bk : bv;
                #pragma unroll
                for (int ni = 0; ni < 4; ni++) {
                    #pragma unroll
                    for (int j = 0; j < 4; j++) {
                        int row = row0 + lg * 4 + j;
                        int cc = w * 64 + ni * 16 + lr;
                        float val = accT[ni][j] + bp[cc];
                        int bb = row >> 11, tt = row & (T_ - 1);
                        int hh = cc >> 6, dh = cc & 63;
                        qkv[(size_t)sel * NTOK * D_ +
                            ((((size_t)bb * H_ + hh) * T_) + tt) * DH_ + dh] = f2bf(val);
                    }
                    accT[ni] = (f32x4){0.f, 0.f, 0.f, 0.f};
                }
            }
        }
    }
}

// ================= attention: QBLK=32, key-parity split over wave pairs, balanced =====
__global__ __launch_bounds__(256) void attn_kernel(
    const u16* __restrict__ q, const u16* __restrict__ k,
    const u16* __restrict__ v, u16* __restrict__ y)
{
    int linear = blockIdx.y * gridDim.x + blockIdx.x;   // 0..511
    int half = linear >> 8, rem = linear & 255;
    int qt_raw = rem & 63;
    int qt = half ? 63 - qt_raw : qt_raw;
    int bh = (rem >> 6) + half * 4;
    int bidx = bh >> 2, h = bh & 3;
    const u16* qp = q + (size_t)bh * T_ * DH_;
    const u16* kp = k + (size_t)bh * T_ * DH_;
    const u16* vp = v + (size_t)bh * T_ * DH_;

    int nch = (qt + 2) >> 1;

    __shared__ u16 Qs[32*64];
    __shared__ u16 Ks[2][2][64*64];
    __shared__ u16 VT[2][64*72];
    __shared__ u16 Ps[4][16*72];

    int tid = threadIdx.x;
    int lane = tid & 63, w = tid >> 6;
    int lr = lane & 15, lg = lane >> 4;
    int p = w >> 1;
    int rh = w & 1;
    int cnt0 = (nch + 1) >> 1, cnt1 = nch >> 1;
    int mycnt = p ? cnt1 : cnt0;
    int maxit = cnt0;

    int pp = tid >> 7;
    int ppcnt = pp ? cnt1 : cnt0;
    int vkey = tid & 63;
    int vdh0 = ((tid >> 6) & 1) * 8;

    {
        int o16 = tid, r = o16 >> 3;
        int sw = ((o16 & 7) << 4) ^ ((r & 7) << 4);
        GLOAD16(qp + (size_t)(qt * 32 + r) * DH_ + (sw >> 1), &Qs[o16 * 8]);
    }
    #pragma unroll
    for (int pr = 0; pr < 2; pr++) {
        int c = min(pr, nch - 1);
        #pragma unroll
        for (int i = 0; i < 2; i++) {
            int o16 = tid + i * 256, r = o16 >> 3;
            int sw = ((o16 & 7) << 4) ^ ((r & 7) << 4);
            GLOAD16(kp + (size_t)(c * 64 + r) * DH_ + (sw >> 1), &Ks[0][pr][o16 * 8]);
        }
    }
    bf16x8 vr[4];
    {
        int c = min(pp, nch - 1);
        #pragma unroll
        for (int g = 0; g < 4; g++)
            vr[g] = *(const bf16x8*)(vp + (size_t)(c * 64 + vkey) * DH_ + vdh0 + g * 16);
    }
    __syncthreads();
    #pragma unroll
    for (int g = 0; g < 4; g++)
        #pragma unroll
        for (int e = 0; e < 8; e++)
            VT[pp][(vdh0 + g * 16 + e) * 72 + vkey] = (u16)vr[g][e];
    bf16x8 qa[2];
    #pragma unroll
    for (int ks = 0; ks < 2; ks++) {
        int rr = rh * 16 + lr;
        qa[ks] = *(const bf16x8*)(Qs + rr * 64 + (((ks * 64 + lg * 16) ^ ((rr & 7) << 4)) >> 1));
    }
    __syncthreads();

    float m[4], lden[4];
    f32x4 o[4] = {};
    #pragma unroll
    for (int j = 0; j < 4; j++) { m[j] = -1e30f; lden[j] = 0.0f; }

    for (int it = 0; it < maxit; it++) {
        int cur = it & 1;
        if (it + 1 < maxit) {
            #pragma unroll
            for (int pr = 0; pr < 2; pr++) {
                int c = min(2 * (it + 1) + pr, nch - 1);
                #pragma unroll
                for (int i = 0; i < 2; i++) {
                    int o16 = tid + i * 256, r = o16 >> 3;
                    int sw = ((o16 & 7) << 4) ^ ((r & 7) << 4);
                    GLOAD16(kp + (size_t)(c * 64 + r) * DH_ + (sw >> 1), &Ks[cur ^ 1][pr][o16 * 8]);
                }
            }
        }
        bool vnext = (it + 1 < ppcnt);
        if (vnext) {
            int c = 2 * (it + 1) + pp;
            #pragma unroll
            for (int g = 0; g < 4; g++)
                vr[g] = *(const bf16x8*)(vp + (size_t)(c * 64 + vkey) * DH_ + vdh0 + g * 16);
        }

        bool act = (it < mycnt);
        if (act) {
            int myc = 2 * it + p;
            f32x4 sc[4];
            #pragma unroll
            for (int ct = 0; ct < 4; ct++) {
                f32x4 s = {};
                __builtin_amdgcn_s_setprio(1);
                #pragma unroll
                for (int ks = 0; ks < 2; ks++) {
                    int rr = ct * 16 + lr;
                    bf16x8 kb = *(const bf16x8*)(&Ks[cur][p][rr * 64 + (((ks * 64 + lg * 16) ^ ((rr & 7) << 4)) >> 1)]);
                    s = __builtin_amdgcn_mfma_f32_16x16x32_bf16(qa[ks], kb, s, 0, 0, 0);
                }
                __builtin_amdgcn_s_setprio(0);
                sc[ct] = s;
            }
            float mloc[4];
            #pragma unroll
            for (int j = 0; j < 4; j++) mloc[j] = -1e30f;
            #pragma unroll
            for (int ct = 0; ct < 4; ct++)
                #pragma unroll
                for (int j = 0; j < 4; j++) {
                    float s = sc[ct][j] * 0.125f;
                    int key = myc * 64 + ct * 16 + lr;
                    int qrow = qt * 32 + rh * 16 + lg * 4 + j;
                    if (key > qrow) s = -1e30f;
                    sc[ct][j] = s;
                    mloc[j] = fmaxf(mloc[j], s);
                }
            #pragma unroll
            for (int j = 0; j < 4; j++) {
                mloc[j] = fmaxf(mloc[j], __shfl_xor(mloc[j], 1));
                mloc[j] = fmaxf(mloc[j], __shfl_xor(mloc[j], 2));
                mloc[j] = fmaxf(mloc[j], __shfl_xor(mloc[j], 4));
                mloc[j] = fmaxf(mloc[j], __shfl_xor(mloc[j], 8));
            }
            float f[4], rs[4];
            #pragma unroll
            for (int j = 0; j < 4; j++) {
                float nm = fmaxf(m[j], mloc[j]);
                f[j] = __expf(m[j] - nm);
                m[j] = nm;
                rs[j] = 0.0f;
            }
            #pragma unroll
            for (int ct = 0; ct < 4; ct++)
                #pragma unroll
                for (int j = 0; j < 4; j++) {
                    float pv = __expf(sc[ct][j] - m[j]);
                    rs[j] += pv;
                    Ps[w][(lg * 4 + j) * 72 + ct * 16 + lr] = f2bf(pv);
                }
            #pragma unroll
            for (int j = 0; j < 4; j++) {
                rs[j] += __shfl_xor(rs[j], 1);
                rs[j] += __shfl_xor(rs[j], 2);
                rs[j] += __shfl_xor(rs[j], 4);
                rs[j] += __shfl_xor(rs[j], 8);
                lden[j] = lden[j] * f[j] + rs[j];
            }
            #pragma unroll
            for (int dt = 0; dt < 4; dt++)
                #pragma unroll
                for (int j = 0; j < 4; j++)
                    o[dt][j] *= f[j];
            #pragma unroll
            for (int ks = 0; ks < 2; ks++) {
                bf16x8 pa = *(const bf16x8*)(&Ps[w][lr * 72 + ks * 32 + lg * 8]);
                __builtin_amdgcn_s_setprio(1);
                #pragma unroll
                for (int dt = 0; dt < 4; dt++) {
                    bf16x8 vb = *(const bf16x8*)(&VT[p][(dt * 16 + lr) * 72 + ks * 32 + lg * 8]);
                    o[dt] = __builtin_amdgcn_mfma_f32_16x16x32_bf16(pa, vb, o[dt], 0, 0, 0);
                }
                __builtin_amdgcn_s_setprio(0);
            }
        }
        __syncthreads();
        if (vnext) {
            #pragma unroll
            for (int g = 0; g < 4; g++)
                #pragma unroll
                for (int e = 0; e < 8; e++)
                    VT[pp][(vdh0 + g * 16 + e) * 72 + vkey] = (u16)vr[g][e];
        }
        __syncthreads();
    }

    float* mg = (float*)&Ks[0][0][0];
    if (p == 1) {
        int base = (rh * 64 + lane) * 24;
        #pragma unroll
        for (int dt = 0; dt < 4; dt++)
            #pragma unroll
            for (int j = 0; j < 4; j++)
                mg[base + dt * 4 + j] = o[dt][j];
        #pragma unroll
        for (int j = 0; j < 4; j++) { mg[base + 16 + j] = m[j]; mg[base + 20 + j] = lden[j]; }
    }
    __syncthreads();
    if (p == 0) {
        int base = (rh * 64 + lane) * 24;
        #pragma unroll
        for (int j = 0; j < 4; j++) {
            float m1 = mg[base + 16 + j];
            float l1 = mg[base + 20 + j];
            float mf = fmaxf(m[j], m1);
            float e0 = __expf(m[j] - mf), e1 = __expf(m1 - mf);
            float inv = 1.0f / (lden[j] * e0 + l1 * e1);
            int qrow = qt * 32 + rh * 16 + lg * 4 + j;
            size_t ybase = ((size_t)(bidx * T_ + qrow)) * D_ + h * DH_;
            #pragma unroll
            for (int dt = 0; dt < 4; dt++) {
                float of = (o[dt][j] * e0 + mg[base + dt * 4 + j] * e1) * inv;
                y[ybase + dt * 16 + lr] = f2bf(of);
            }
        }
    }
}

// ================= head GEMM: col-major-within-XCD mapping, nt stores ============
__global__ __launch_bounds__(256) void head_gemm(
    const u16* __restrict__ A, const u16* __restrict__ BT,
    const float* __restrict__ bias, float* __restrict__ C,
    int M, int N, int K)
{
    __shared__ u16 As[2][128*64];
    __shared__ u16 Bs[2][128*64];
    int tid = threadIdx.x;
    int lane = tid & 63, w = tid >> 6;
    int lr = lane & 15, lg = lane >> 4;
    int wm = w >> 1, wn = w & 1;

    int orig = blockIdx.y * gridDim.x + blockIdx.x;   // 8000 blocks
    int bid = xcd_swizzle(orig, 8000);
    int col0 = (bid >> 5) * 128;
    int row0 = (bid & 31) * 128;

    f32x4 acc[4][4] = {};

    auto stage = [&](int buf, int k0) {
        #pragma unroll
        for (int i = 0; i < 4; i++) {
            int o16 = tid + i * 256;
            int r = o16 >> 3;
            int sw = ((o16 & 7) << 4) ^ ((r & 7) << 4);
            GLOAD16(A + (size_t)(row0 + r) * K + k0 + (sw >> 1), &As[buf][o16 * 8]);
            GLOAD16(BT + (size_t)(col0 + r) * K + k0 + (sw >> 1), &Bs[buf][o16 * 8]);
        }
    };

    stage(0, 0);
    int nk = K >> 6;
    for (int t = 0; t < nk; t++) {
        int cur = t & 1;
        __syncthreads();
        if (t + 1 < nk) stage(cur ^ 1, (t + 1) << 6);
        #pragma unroll
        for (int ks = 0; ks < 2; ks++) {
            bf16x8 af[4], bfr[4];
            #pragma unroll
            for (int mi = 0; mi < 4; mi++) {
                int rr = wm * 64 + mi * 16 + lr;
                af[mi] = *(const bf16x8*)(&As[cur][rr * 64 + (((ks * 64 + lg * 16) ^ ((rr & 7) << 4)) >> 1)]);
            }
            #pragma unroll
            for (int ni = 0; ni < 4; ni++) {
                int rr = wn * 64 + ni * 16 + lr;
                bfr[ni] = *(const bf16x8*)(&Bs[cur][rr * 64 + (((ks * 64 + lg * 16) ^ ((rr & 7) << 4)) >> 1)]);
            }
            __builtin_amdgcn_s_setprio(1);
            #pragma unroll
            for (int mi = 0; mi < 4; mi++)
                #pragma unroll
                for (int ni = 0; ni < 4; ni++)
                    acc[mi][ni] = __builtin_amdgcn_mfma_f32_16x16x32_bf16(af[mi], bfr[ni], acc[mi][ni], 0, 0, 0);
            __builtin_amdgcn_s_setprio(0);
        }
    }

    #pragma unroll
    for (int mi = 0; mi < 4; mi++)
        #pragma unroll
        for (int ni = 0; ni < 4; ni++)
            #pragma unroll
            for (int j = 0; j < 4; j++) {
                int row = row0 + wm * 64 + mi * 16 + lg * 4 + j;
                int col = col0 + wn * 64 + ni * 16 + lr;
                __builtin_nontemporal_store(acc[mi][ni][j] + bias[col], &C[(size_t)row * N + col]);
            }
}

// ================= host launch =================
extern "C" void kernel_launch(void* const* d_in, const int* in_sizes, int n_in,
                              void* d_out, int out_size, void* d_ws, size_t ws_size,
                              hipStream_t stream)
{
    const int*   idx  = (const int*)d_in[0];
    const float* tok  = (const float*)d_in[1];
    const float* pos  = (const float*)d_in[2];
    const float* Wq   = (const float*)d_in[3];
    const float* bq   = (const float*)d_in[4];
    const float* Wk   = (const float*)d_in[5];
    const float* bk   = (const float*)d_in[6];
    const float* Wv   = (const float*)d_in[7];
    const float* bv   = (const float*)d_in[8];
    const float* Wo   = (const float*)d_in[9];
    const float* bo   = (const float*)d_in[10];
    const float* ln1g = (const float*)d_in[11];
    const float* ln1b = (const float*)d_in[12];
    const float* W1   = (const float*)d_in[13];
    const float* b1   = (const float*)d_in[14];
    const float* W2   = (const float*)d_in[15];
    const float* b2   = (const float*)d_in[16];
    const float* ln2g = (const float*)d_in[17];
    const float* ln2b = (const float*)d_in[18];
    const float* lnfg = (const float*)d_in[19];
    const float* lnfb = (const float*)d_in[20];
    const float* hW   = (const float*)d_in[21];
    const float* hb   = (const float*)d_in[22];

    char* p = (char*)d_ws;
    float* x     = (float*)p;           p += (size_t)NTOK * D_ * 4;
    u16* hbuf    = (u16*)p;             p += (size_t)NTOK * D_ * 2;
    u16* qkvbuf  = (u16*)p;             p += (size_t)3 * NTOK * D_ * 2;
    u16* ybuf    = (u16*)p;             p += (size_t)NTOK * D_ * 2;
    u16* ff      = (u16*)p;             p += (size_t)NTOK * DF_ * 2;
    u16* WqkvT   = (u16*)p;             p += (size_t)L_ * 768 * D_ * 2;
    u16* WoT     = (u16*)p;             p += (size_t)L_ * D_ * D_ * 2;
    u16* W1T     = (u16*)p;             p += (size_t)L_ * D_ * DF_ * 2;
    u16* W2T     = (u16*)p;             p += (size_t)L_ * DF_ * D_ * 2;
    u16* hWT     = (u16*)p;             p += (size_t)V_ * D_ * 2;

    u16* qbuf = qkvbuf;
    u16* kbuf = qkvbuf + (size_t)NTOK * D_;
    u16* vbuf = qkvbuf + (size_t)2 * NTOK * D_;

    prep_kernel<<<5536, 256, 0, stream>>>(Wq, Wk, Wv, Wo, W1, W2, hW,
                                          WqkvT, WoT, W1T, W2T, hWT);

    embed_qkv_kernel<<<256, 256, 0, stream>>>(idx, tok, pos, ln1g, ln1b,
                                              WqkvT, bq, bk, bv, x, qkvbuf);

    dim3 gAttn(64, 8);                   // 512 balanced blocks
    for (int l = 0; l < L_; l++) {
        attn_kernel<<<gAttn, 256, 0, stream>>>(qbuf, kbuf, vbuf, ybuf);
        woff1_kernel<<<256, 256, 0, stream>>>(ybuf, WoT + (size_t)l * 65536, bo + l * D_,
                                              W1T + (size_t)l * 262144, b1 + l * DF_,
                                              ln2g + l * D_, ln2b + l * D_, x, ff);
        if (l < L_ - 1) {
            ff2qkv_kernel<false><<<256, 256, 0, stream>>>(
                ff, W2T + (size_t)l * 262144, b2 + l * D_,
                ln1g + (l + 1) * D_, ln1b + (l + 1) * D_,
                WqkvT + (size_t)(l + 1) * 196608,
                bq + (l + 1) * D_, bk + (l + 1) * D_, bv + (l + 1) * D_,
                x, nullptr, qkvbuf);
        } else {
            ff2qkv_kernel<true><<<256, 256, 0, stream>>>(
                ff, W2T + (size_t)l * 262144, b2 + l * D_,
                lnfg, lnfb,
                nullptr, nullptr, nullptr, nullptr,
                x, hbuf, nullptr);
        }
    }

    dim3 gHead(V_ / 128, NTOK / 128);    // (250, 32)
    head_gemm<<<gHead, 256, 0, stream>>>(hbuf, hWT, hb, (float*)d_out, NTOK, V_, D_);
}

// Round 10
// 501.269 us; speedup vs baseline: 1.3125x; 1.3125x over previous
//
#include <hip/hip_runtime.h>
#include <hip/hip_bf16.h>
#include <math.h>

#define V_   32000
#define L_   4
#define H_   4
#define D_   256
#define DF_  1024
#define B_   2
#define T_   2048
#define DH_  64
#define NTOK (B_*T_)   // 4096

typedef __attribute__((ext_vector_type(8))) short bf16x8;
typedef __attribute__((ext_vector_type(4))) float f32x4;
typedef unsigned short u16;

#define GLOAD16(gsrc, ldst) \
  __builtin_amdgcn_global_load_lds((const __attribute__((address_space(1))) void*)(gsrc), \
                                   (__attribute__((address_space(3))) void*)(ldst), 16, 0, 0)

// counted-vmcnt stage boundary (T4): barrier_A -> issue -> vmcnt(N)+lgkm -> barrier_B
#define BAR_A()   asm volatile("s_barrier" ::: "memory")
#define WAITB(N)  do { asm volatile("s_waitcnt vmcnt(" #N ") lgkmcnt(0)" ::: "memory"); \
                       asm volatile("s_barrier" ::: "memory"); } while (0)

__device__ __forceinline__ u16 f2bf(float f) {
    unsigned int u = __builtin_bit_cast(unsigned int, f);
    u = (u + 0x7fff + ((u >> 16) & 1)) >> 16;   // RNE
    return (u16)u;
}

__device__ __forceinline__ int xcd_swizzle(int orig, int nwg) {
    return ((nwg & 7) == 0) ? ((orig & 7) * (nwg >> 3) + (orig >> 3)) : orig;
}

// ================= prep: weight transposes f32[K,N] -> bf16[N,K], 64k x 32n tiles =====
__global__ __launch_bounds__(256) void prep_kernel(
    const float* __restrict__ Wq, const float* __restrict__ Wk,
    const float* __restrict__ Wv, const float* __restrict__ Wo,
    const float* __restrict__ W1, const float* __restrict__ W2,
    const float* __restrict__ hW,
    u16* __restrict__ WqkvT, u16* __restrict__ WoT,
    u16* __restrict__ W1T, u16* __restrict__ W2T, u16* __restrict__ hWT)
{
    int b = blockIdx.x;
    const float* src; u16* dst; int K, N, k0, n0;
    if (b < 512) {
        int m = b >> 5, t = b & 31;
        int wt = m & 3, l = m >> 2;
        K = 256; N = 256;
        src = (wt == 0 ? Wq : wt == 1 ? Wk : wt == 2 ? Wv : Wo) + (size_t)l * 65536;
        dst = (wt < 3) ? WqkvT + (size_t)l * 196608 + (size_t)wt * 65536
                       : WoT + (size_t)l * 65536;
        k0 = (t >> 3) * 64; n0 = (t & 7) * 32;
    } else if (b < 1024) {
        int bb = b - 512; int l = bb >> 7, t = bb & 127;
        K = 256; N = 1024;
        src = W1 + (size_t)l * 262144; dst = W1T + (size_t)l * 262144;
        k0 = (t >> 5) * 64; n0 = (t & 31) * 32;
    } else if (b < 1536) {
        int bb = b - 1024; int l = bb >> 7, t = bb & 127;
        K = 1024; N = 256;
        src = W2 + (size_t)l * 262144; dst = W2T + (size_t)l * 262144;
        k0 = (t >> 3) * 64; n0 = (t & 7) * 32;
    } else {
        int bb = b - 1536;
        K = 256; N = 32000;
        src = hW; dst = hWT;
        k0 = (bb / 1000) * 64; n0 = (bb % 1000) * 32;
    }
    __shared__ float tile[64][33];
    int tid = threadIdx.x;
    int tc = tid & 31, tr = tid >> 5;
    #pragma unroll
    for (int i = 0; i < 8; i++)
        tile[tr + i*8][tc] = src[(size_t)(k0 + tr + i*8) * N + n0 + tc];
    __syncthreads();
    int kc = tid & 63, nr = tid >> 6;
    #pragma unroll
    for (int i = 0; i < 8; i++)
        dst[(size_t)(n0 + nr + i*4) * K + k0 + kc] = f2bf(tile[kc][nr + i*4]);
}

// ================= embed + LN1(l0) + QKV(l0): 256 blocks x 256t, 16 rows/block =========
__global__ __launch_bounds__(256) void embed_qkv_kernel(
    const int* __restrict__ idx, const float* __restrict__ tok, const float* __restrict__ pos,
    const float* __restrict__ g, const float* __restrict__ bta,
    const u16* __restrict__ WqkvT0,
    const float* __restrict__ bq, const float* __restrict__ bk, const float* __restrict__ bv,
    float* __restrict__ x, u16* __restrict__ qkv)
{
    __shared__ u16 Bs[2][256*64];
    __shared__ u16 hS[16][264];

    int tid = threadIdx.x;
    int lane = tid & 63, w = tid >> 6;
    int lr = lane & 15, lg = lane >> 4;
    int bid = xcd_swizzle(blockIdx.x, 256);
    int row0 = bid * 16;

    {
        int grow = tid >> 4;
        int gcol = (tid & 15) * 16;
        int n = row0 + grow;
        int t = n & (T_ - 1);
        int id = idx[n];
        float vv[16];
        #pragma unroll
        for (int i = 0; i < 4; i++) {
            float4 a = *(const float4*)(tok + (size_t)id * D_ + gcol + i * 4);
            float4 b = *(const float4*)(pos + (size_t)t * D_ + gcol + i * 4);
            vv[i*4+0] = a.x + b.x; vv[i*4+1] = a.y + b.y;
            vv[i*4+2] = a.z + b.z; vv[i*4+3] = a.w + b.w;
        }
        float s = 0.f, q = 0.f;
        #pragma unroll
        for (int i = 0; i < 16; i++) { s += vv[i]; q += vv[i]*vv[i]; }
        #pragma unroll
        for (int o = 1; o <= 8; o <<= 1) { s += __shfl_xor(s, o); q += __shfl_xor(q, o); }
        float mu = s * (1.0f / D_);
        float var = q * (1.0f / D_) - mu * mu;
        float ri = rsqrtf(var + 1e-5f);
        #pragma unroll
        for (int i = 0; i < 16; i++) {
            x[(size_t)n * D_ + gcol + i] = vv[i];
            hS[grow][gcol + i] = f2bf((vv[i] - mu) * ri * g[gcol + i] + bta[gcol + i]);
        }
    }

    auto stageQ = [&](int buf, int u) {
        const u16* BT = WqkvT0 + (size_t)(u >> 2) * 65536;
        int k0 = (u & 3) * 64;
        #pragma unroll
        for (int i = 0; i < 8; i++) {
            int o16 = tid + i * 256;
            int r = o16 >> 3;
            int sw = ((o16 & 7) << 4) ^ ((r & 7) << 4);
            GLOAD16(BT + (size_t)r * 256 + k0 + (sw >> 1), &Bs[buf][o16 * 8]);
        }
    };
    auto afH = [&](int t, int ks) -> bf16x8 {
        return *(const bf16x8*)(&hS[lr][(t * 128 + ks * 64 + lg * 16) >> 1]);
    };
    auto bfr = [&](int buf, int ni, int ks) -> bf16x8 {
        int rr = w * 64 + ni * 16 + lr;
        return *(const bf16x8*)(&Bs[buf][rr * 64 + (((ks * 64 + lg * 16) ^ ((rr & 7) << 4)) >> 1)]);
    };

    stageQ(0, 0);
    f32x4 acc[4] = {};
    for (int u = 0; u < 12; u++) {
        BAR_A();
        if (u + 1 < 12) { stageQ((u + 1) & 1, u + 1); WAITB(8); }
        else            { WAITB(0); }
        int t = u & 3;
        #pragma unroll
        for (int ks = 0; ks < 2; ks++) {
            bf16x8 a = afH(t, ks);
            __builtin_amdgcn_s_setprio(1);
            #pragma unroll
            for (int ni = 0; ni < 4; ni++)
                acc[ni] = __builtin_amdgcn_mfma_f32_16x16x32_bf16(a, bfr(u & 1, ni, ks), acc[ni], 0, 0, 0);
            __builtin_amdgcn_s_setprio(0);
        }
        if (t == 3) {
            int sel = u >> 2;
            const float* bp = sel == 0 ? bq : sel == 1 ? bk : bv;
            #pragma unroll
            for (int ni = 0; ni < 4; ni++) {
                #pragma unroll
                for (int j = 0; j < 4; j++) {
                    int row = row0 + lg * 4 + j;
                    int cc = w * 64 + ni * 16 + lr;
                    float v = acc[ni][j] + bp[cc];
                    int bb = row >> 11, tt = row & (T_ - 1);
                    int hh = cc >> 6, dh = cc & 63;
                    qkv[(size_t)sel * NTOK * D_ +
                        ((((size_t)bb * H_ + hh) * T_) + tt) * DH_ + dh] = f2bf(v);
                }
                acc[ni] = (f32x4){0.f, 0.f, 0.f, 0.f};
            }
        }
    }
}

// ================= Wo + residual + LN2: 256 blocks x 256t, 16 rows/block ==========
__global__ __launch_bounds__(256) void wo_ln_kernel(
    const u16* __restrict__ ybuf, const u16* __restrict__ WoT, const float* __restrict__ bo,
    const float* __restrict__ ln2g, const float* __restrict__ ln2b,
    float* __restrict__ x, u16* __restrict__ hbuf)
{
    __shared__ u16 As[2][16*64];
    __shared__ u16 Bs[2][256*64];
    __shared__ float sred[4][16], qred[4][16];

    int tid = threadIdx.x;
    int lane = tid & 63, w = tid >> 6;
    int lr = lane & 15, lg = lane >> 4;
    int bid = xcd_swizzle(blockIdx.x, 256);
    int row0 = bid * 16;

    auto stage = [&](int buf, int k0) {
        #pragma unroll
        for (int i = 0; i < 8; i++) {
            int o16 = tid + i * 256;
            int r = o16 >> 3;
            int sw = ((o16 & 7) << 4) ^ ((r & 7) << 4);
            GLOAD16(WoT + (size_t)r * 256 + k0 + (sw >> 1), &Bs[buf][o16 * 8]);
        }
        if (tid < 128) {
            int r = tid >> 3;
            int sw = ((tid & 7) << 4) ^ ((r & 7) << 4);
            GLOAD16(ybuf + (size_t)(row0 + r) * 256 + k0 + (sw >> 1), &As[buf][tid * 8]);
        }
    };
    auto afA = [&](int buf, int ks) -> bf16x8 {
        return *(const bf16x8*)(&As[buf][lr * 64 + (((ks * 64 + lg * 16) ^ ((lr & 7) << 4)) >> 1)]);
    };
    auto bfr = [&](int buf, int ni, int ks) -> bf16x8 {
        int rr = w * 64 + ni * 16 + lr;
        return *(const bf16x8*)(&Bs[buf][rr * 64 + (((ks * 64 + lg * 16) ^ ((rr & 7) << 4)) >> 1)]);
    };

    stage(0, 0);
    f32x4 acc[4] = {};
    for (int t = 0; t < 4; t++) {
        BAR_A();
        if (t + 1 < 4) { stage((t + 1) & 1, (t + 1) * 64); WAITB(8); }
        else           { WAITB(0); }
        #pragma unroll
        for (int ks = 0; ks < 2; ks++) {
            bf16x8 a = afA(t & 1, ks);
            __builtin_amdgcn_s_setprio(1);
            #pragma unroll
            for (int ni = 0; ni < 4; ni++)
                acc[ni] = __builtin_amdgcn_mfma_f32_16x16x32_bf16(a, bfr(t & 1, ni, ks), acc[ni], 0, 0, 0);
            __builtin_amdgcn_s_setprio(0);
        }
    }

    float vals[4][4];
    float rs[4] = {0,0,0,0}, rq[4] = {0,0,0,0};
    #pragma unroll
    for (int ni = 0; ni < 4; ni++)
        #pragma unroll
        for (int j = 0; j < 4; j++) {
            int row = row0 + lg * 4 + j;
            int col = w * 64 + ni * 16 + lr;
            float v = acc[ni][j] + bo[col] + x[(size_t)row * D_ + col];
            x[(size_t)row * D_ + col] = v;
            vals[ni][j] = v;
            rs[j] += v; rq[j] += v * v;
        }
    #pragma unroll
    for (int j = 0; j < 4; j++)
        #pragma unroll
        for (int o = 1; o <= 8; o <<= 1) { rs[j] += __shfl_xor(rs[j], o); rq[j] += __shfl_xor(rq[j], o); }
    if (lr == 0)
        #pragma unroll
        for (int j = 0; j < 4; j++) { sred[w][lg*4 + j] = rs[j]; qred[w][lg*4 + j] = rq[j]; }
    __syncthreads();
    #pragma unroll
    for (int j = 0; j < 4; j++) {
        int r = lg * 4 + j;
        float mu = (sred[0][r] + sred[1][r] + sred[2][r] + sred[3][r]) * (1.0f / D_);
        float var = (qred[0][r] + qred[1][r] + qred[2][r] + qred[3][r]) * (1.0f / D_) - mu * mu;
        float ri = rsqrtf(var + 1e-5f);
        int row = row0 + r;
        #pragma unroll
        for (int ni = 0; ni < 4; ni++) {
            int col = w * 64 + ni * 16 + lr;
            hbuf[(size_t)row * D_ + col] = f2bf((vals[ni][j] - mu) * ri * ln2g[col] + ln2b[col]);
        }
    }
}

// ================= FF1 + GELU: 64x64 tiles, 1024 blocks =================
__global__ __launch_bounds__(256) void ff1_kernel(
    const u16* __restrict__ A, const u16* __restrict__ BT,
    const float* __restrict__ bias, u16* __restrict__ C)
{
    __shared__ u16 As[2][64*64];
    __shared__ u16 Bs[2][64*64];
    int tid = threadIdx.x;
    int lane = tid & 63, w = tid >> 6;
    int lr = lane & 15, lg = lane >> 4;
    int wm = w >> 1, wn = w & 1;

    int gx = gridDim.x;
    int nwg = gx * gridDim.y;
    int orig = blockIdx.y * gx + blockIdx.x;
    int bid = xcd_swizzle(orig, nwg);
    int row0 = (bid / gx) * 64, col0 = (bid % gx) * 64;

    auto stage = [&](int buf, int k0) {
        #pragma unroll
        for (int i = 0; i < 2; i++) {
            int o16 = tid + i * 256;
            int r = o16 >> 3;
            int sw = ((o16 & 7) << 4) ^ ((r & 7) << 4);
            GLOAD16(A + (size_t)(row0 + r) * 256 + k0 + (sw >> 1), &As[buf][o16 * 8]);
            GLOAD16(BT + (size_t)(col0 + r) * 256 + k0 + (sw >> 1), &Bs[buf][o16 * 8]);
        }
    };

    stage(0, 0);
    f32x4 acc[2][2] = {};
    for (int t = 0; t < 4; t++) {
        BAR_A();
        if (t + 1 < 4) { stage((t + 1) & 1, (t + 1) * 64); WAITB(4); }
        else           { WAITB(0); }
        #pragma unroll
        for (int ks = 0; ks < 2; ks++) {
            bf16x8 af[2], bfv[2];
            #pragma unroll
            for (int mi = 0; mi < 2; mi++) {
                int rr = wm * 32 + mi * 16 + lr;
                af[mi] = *(const bf16x8*)(&As[t & 1][rr * 64 + (((ks * 64 + lg * 16) ^ ((rr & 7) << 4)) >> 1)]);
            }
            #pragma unroll
            for (int ni = 0; ni < 2; ni++) {
                int rr = wn * 32 + ni * 16 + lr;
                bfv[ni] = *(const bf16x8*)(&Bs[t & 1][rr * 64 + (((ks * 64 + lg * 16) ^ ((rr & 7) << 4)) >> 1)]);
            }
            __builtin_amdgcn_s_setprio(1);
            #pragma unroll
            for (int mi = 0; mi < 2; mi++)
                #pragma unroll
                for (int ni = 0; ni < 2; ni++)
                    acc[mi][ni] = __builtin_amdgcn_mfma_f32_16x16x32_bf16(af[mi], bfv[ni], acc[mi][ni], 0, 0, 0);
            __builtin_amdgcn_s_setprio(0);
        }
    }

    #pragma unroll
    for (int mi = 0; mi < 2; mi++)
        #pragma unroll
        for (int ni = 0; ni < 2; ni++)
            #pragma unroll
            for (int j = 0; j < 4; j++) {
                int row = row0 + wm * 32 + mi * 16 + lg * 4 + j;
                int col = col0 + wn * 32 + ni * 16 + lr;
                float v = acc[mi][ni][j] + bias[col];
                v = 0.5f * v * (1.0f + erff(v * 0.70710678118f));
                C[(size_t)row * DF_ + col] = f2bf(v);
            }
}

// ================= FF2 + residual + LN(next) + QKV(next): 256 blocks, 16 rows =========
template<bool LAST>
__global__ __launch_bounds__(256) void ff2qkv_kernel(
    const u16* __restrict__ ff, const u16* __restrict__ W2T, const float* __restrict__ b2,
    const float* __restrict__ lng, const float* __restrict__ lnb,
    const u16* __restrict__ WqkvT,
    const float* __restrict__ bq, const float* __restrict__ bk, const float* __restrict__ bv,
    float* __restrict__ x, u16* __restrict__ hout, u16* __restrict__ qkv)
{
    __shared__ u16 As[2][16*64];
    __shared__ u16 Bs[2][256*64];
    __shared__ u16 hS[16][264];
    __shared__ float sred[4][16], qred[4][16];

    int tid = threadIdx.x;
    int lane = tid & 63, w = tid >> 6;
    int lr = lane & 15, lg = lane >> 4;
    int bid = xcd_swizzle(blockIdx.x, 256);
    int row0 = bid * 16;

    auto stageB = [&](int buf, const u16* BT, int K, int k0) {
        #pragma unroll
        for (int i = 0; i < 8; i++) {
            int o16 = tid + i * 256;
            int r = o16 >> 3;
            int sw = ((o16 & 7) << 4) ^ ((r & 7) << 4);
            GLOAD16(BT + (size_t)r * K + k0 + (sw >> 1), &Bs[buf][o16 * 8]);
        }
    };
    auto stageA = [&](int buf, int k0) {
        if (tid < 128) {
            int r = tid >> 3;
            int sw = ((tid & 7) << 4) ^ ((r & 7) << 4);
            GLOAD16(ff + (size_t)(row0 + r) * DF_ + k0 + (sw >> 1), &As[buf][tid * 8]);
        }
    };
    auto prefetch = [&](int u) {
        if (u < 16) { stageA(u & 1, u * 64); stageB(u & 1, W2T, 1024, u * 64); }
        else if (!LAST && u < 28) {
            int v = u - 16;
            stageB(u & 1, WqkvT + (size_t)(v >> 2) * 65536, 256, (v & 3) * 64);
        }
    };
    auto afA = [&](int buf, int ks) -> bf16x8 {
        return *(const bf16x8*)(&As[buf][lr * 64 + (((ks * 64 + lg * 16) ^ ((lr & 7) << 4)) >> 1)]);
    };
    auto afH = [&](int t, int ks) -> bf16x8 {
        return *(const bf16x8*)(&hS[lr][(t * 128 + ks * 64 + lg * 16) >> 1]);
    };
    auto bfr = [&](int buf, int ni, int ks) -> bf16x8 {
        int rr = w * 64 + ni * 16 + lr;
        return *(const bf16x8*)(&Bs[buf][rr * 64 + (((ks * 64 + lg * 16) ^ ((rr & 7) << 4)) >> 1)]);
    };

    prefetch(0);
    f32x4 acc[4] = {};
    for (int u = 0; u < 16; u++) {
        BAR_A();
        prefetch(u + 1);        // u+1 <= 16: always issues
        WAITB(8);
        #pragma unroll
        for (int ks = 0; ks < 2; ks++) {
            bf16x8 a = afA(u & 1, ks);
            __builtin_amdgcn_s_setprio(1);
            #pragma unroll
            for (int ni = 0; ni < 4; ni++)
                acc[ni] = __builtin_amdgcn_mfma_f32_16x16x32_bf16(a, bfr(u & 1, ni, ks), acc[ni], 0, 0, 0);
            __builtin_amdgcn_s_setprio(0);
        }
    }

    {
        float vals[4][4];
        float rs[4] = {0,0,0,0}, rq[4] = {0,0,0,0};
        #pragma unroll
        for (int ni = 0; ni < 4; ni++)
            #pragma unroll
            for (int j = 0; j < 4; j++) {
                int row = row0 + lg * 4 + j;
                int col = w * 64 + ni * 16 + lr;
                float v = acc[ni][j] + b2[col] + x[(size_t)row * D_ + col];
                x[(size_t)row * D_ + col] = v;
                vals[ni][j] = v;
                rs[j] += v; rq[j] += v * v;
            }
        #pragma unroll
        for (int j = 0; j < 4; j++)
            #pragma unroll
            for (int o = 1; o <= 8; o <<= 1) { rs[j] += __shfl_xor(rs[j], o); rq[j] += __shfl_xor(rq[j], o); }
        if (lr == 0)
            #pragma unroll
            for (int j = 0; j < 4; j++) { sred[w][lg*4 + j] = rs[j]; qred[w][lg*4 + j] = rq[j]; }
        __syncthreads();
        #pragma unroll
        for (int j = 0; j < 4; j++) {
            int r = lg * 4 + j;
            float mu = (sred[0][r] + sred[1][r] + sred[2][r] + sred[3][r]) * (1.0f / D_);
            float var = (qred[0][r] + qred[1][r] + qred[2][r] + qred[3][r]) * (1.0f / D_) - mu * mu;
            float ri = rsqrtf(var + 1e-5f);
            #pragma unroll
            for (int ni = 0; ni < 4; ni++) {
                int col = w * 64 + ni * 16 + lr;
                float hv = (vals[ni][j] - mu) * ri * lng[col] + lnb[col];
                if (LAST) hout[(size_t)(row0 + r) * D_ + col] = f2bf(hv);
                else      hS[r][col] = f2bf(hv);
            }
        }
    }

    if constexpr (!LAST) {
        __syncthreads();        // hS writes visible; drains outstanding tile-16/17 loads
        f32x4 accT[4] = {};
        for (int v = 0; v < 12; v++) {
            BAR_A();
            if (v + 1 < 12) { prefetch(16 + v + 1); WAITB(8); }
            else            { WAITB(0); }
            int t = v & 3;
            #pragma unroll
            for (int ks = 0; ks < 2; ks++) {
                bf16x8 a = afH(t, ks);
                __builtin_amdgcn_s_setprio(1);
                #pragma unroll
                for (int ni = 0; ni < 4; ni++)
                    accT[ni] = __builtin_amdgcn_mfma_f32_16x16x32_bf16(a, bfr(v & 1, ni, ks), accT[ni], 0, 0, 0);
                __builtin_amdgcn_s_setprio(0);
            }
            if (t == 3) {
                int sel = v >> 2;
                const float* bp = sel == 0 ? bq : sel == 1 ? bk : bv;
                #pragma unroll
                for (int ni = 0; ni < 4; ni++) {
                    #pragma unroll
                    for (int j = 0; j < 4; j++) {
                        int row = row0 + lg * 4 + j;
                        int cc = w * 64 + ni * 16 + lr;
                        float val = accT[ni][j] + bp[cc];
                        int bb = row >> 11, tt = row & (T_ - 1);
                        int hh = cc >> 6, dh = cc & 63;
                        qkv[(size_t)sel * NTOK * D_ +
                            ((((size_t)bb * H_ + hh) * T_) + tt) * DH_ + dh] = f2bf(val);
                    }
                    accT[ni] = (f32x4){0.f, 0.f, 0.f, 0.f};
                }
            }
        }
    }
}

// ================= attention: QBLK=32, key-parity split over wave pairs, balanced =====
__global__ __launch_bounds__(256) void attn_kernel(
    const u16* __restrict__ q, const u16* __restrict__ k,
    const u16* __restrict__ v, u16* __restrict__ y)
{
    int linear = blockIdx.y * gridDim.x + blockIdx.x;   // 0..511
    int half = linear >> 8, rem = linear & 255;
    int qt_raw = rem & 63;
    int qt = half ? 63 - qt_raw : qt_raw;
    int bh = (rem >> 6) + half * 4;
    int bidx = bh >> 2, h = bh & 3;
    const u16* qp = q + (size_t)bh * T_ * DH_;
    const u16* kp = k + (size_t)bh * T_ * DH_;
    const u16* vp = v + (size_t)bh * T_ * DH_;

    int nch = (qt + 2) >> 1;

    __shared__ u16 Qs[32*64];
    __shared__ u16 Ks[2][2][64*64];
    __shared__ u16 VT[2][64*72];
    __shared__ u16 Ps[4][16*72];

    int tid = threadIdx.x;
    int lane = tid & 63, w = tid >> 6;
    int lr = lane & 15, lg = lane >> 4;
    int p = w >> 1;
    int rh = w & 1;
    int cnt0 = (nch + 1) >> 1, cnt1 = nch >> 1;
    int mycnt = p ? cnt1 : cnt0;
    int maxit = cnt0;

    int pp = tid >> 7;
    int ppcnt = pp ? cnt1 : cnt0;
    int vkey = tid & 63;
    int vdh0 = ((tid >> 6) & 1) * 8;

    {
        int o16 = tid, r = o16 >> 3;
        int sw = ((o16 & 7) << 4) ^ ((r & 7) << 4);
        GLOAD16(qp + (size_t)(qt * 32 + r) * DH_ + (sw >> 1), &Qs[o16 * 8]);
    }
    #pragma unroll
    for (int pr = 0; pr < 2; pr++) {
        int c = min(pr, nch - 1);
        #pragma unroll
        for (int i = 0; i < 2; i++) {
            int o16 = tid + i * 256, r = o16 >> 3;
            int sw = ((o16 & 7) << 4) ^ ((r & 7) << 4);
            GLOAD16(kp + (size_t)(c * 64 + r) * DH_ + (sw >> 1), &Ks[0][pr][o16 * 8]);
        }
    }
    bf16x8 vr[4];
    {
        int c = min(pp, nch - 1);
        #pragma unroll
        for (int g = 0; g < 4; g++)
            vr[g] = *(const bf16x8*)(vp + (size_t)(c * 64 + vkey) * DH_ + vdh0 + g * 16);
    }
    __syncthreads();
    #pragma unroll
    for (int g = 0; g < 4; g++)
        #pragma unroll
        for (int e = 0; e < 8; e++)
            VT[pp][(vdh0 + g * 16 + e) * 72 + vkey] = (u16)vr[g][e];
    bf16x8 qa[2];
    #pragma unroll
    for (int ks = 0; ks < 2; ks++) {
        int rr = rh * 16 + lr;
        qa[ks] = *(const bf16x8*)(Qs + rr * 64 + (((ks * 64 + lg * 16) ^ ((rr & 7) << 4)) >> 1));
    }
    __syncthreads();

    float m[4], lden[4];
    f32x4 o[4] = {};
    #pragma unroll
    for (int j = 0; j < 4; j++) { m[j] = -1e30f; lden[j] = 0.0f; }

    for (int it = 0; it < maxit; it++) {
        int cur = it & 1;
        if (it + 1 < maxit) {
            #pragma unroll
            for (int pr = 0; pr < 2; pr++) {
                int c = min(2 * (it + 1) + pr, nch - 1);
                #pragma unroll
                for (int i = 0; i < 2; i++) {
                    int o16 = tid + i * 256, r = o16 >> 3;
                    int sw = ((o16 & 7) << 4) ^ ((r & 7) << 4);
                    GLOAD16(kp + (size_t)(c * 64 + r) * DH_ + (sw >> 1), &Ks[cur ^ 1][pr][o16 * 8]);
                }
            }
        }
        bool vnext = (it + 1 < ppcnt);
        if (vnext) {
            int c = 2 * (it + 1) + pp;
            #pragma unroll
            for (int g = 0; g < 4; g++)
                vr[g] = *(const bf16x8*)(vp + (size_t)(c * 64 + vkey) * DH_ + vdh0 + g * 16);
        }

        bool act = (it < mycnt);
        if (act) {
            int myc = 2 * it + p;
            f32x4 sc[4];
            #pragma unroll
            for (int ct = 0; ct < 4; ct++) {
                f32x4 s = {};
                __builtin_amdgcn_s_setprio(1);
                #pragma unroll
                for (int ks = 0; ks < 2; ks++) {
                    int rr = ct * 16 + lr;
                    bf16x8 kb = *(const bf16x8*)(&Ks[cur][p][rr * 64 + (((ks * 64 + lg * 16) ^ ((rr & 7) << 4)) >> 1)]);
                    s = __builtin_amdgcn_mfma_f32_16x16x32_bf16(qa[ks], kb, s, 0, 0, 0);
                }
                __builtin_amdgcn_s_setprio(0);
                sc[ct] = s;
            }
            float mloc[4];
            #pragma unroll
            for (int j = 0; j < 4; j++) mloc[j] = -1e30f;
            #pragma unroll
            for (int ct = 0; ct < 4; ct++)
                #pragma unroll
                for (int j = 0; j < 4; j++) {
                    float s = sc[ct][j] * 0.125f;
                    int key = myc * 64 + ct * 16 + lr;
                    int qrow = qt * 32 + rh * 16 + lg * 4 + j;
                    if (key > qrow) s = -1e30f;
                    sc[ct][j] = s;
                    mloc[j] = fmaxf(mloc[j], s);
                }
            #pragma unroll
            for (int j = 0; j < 4; j++) {
                mloc[j] = fmaxf(mloc[j], __shfl_xor(mloc[j], 1));
                mloc[j] = fmaxf(mloc[j], __shfl_xor(mloc[j], 2));
                mloc[j] = fmaxf(mloc[j], __shfl_xor(mloc[j], 4));
                mloc[j] = fmaxf(mloc[j], __shfl_xor(mloc[j], 8));
            }
            float f[4], rs[4];
            #pragma unroll
            for (int j = 0; j < 4; j++) {
                float nm = fmaxf(m[j], mloc[j]);
                f[j] = __expf(m[j] - nm);
                m[j] = nm;
                rs[j] = 0.0f;
            }
            #pragma unroll
            for (int ct = 0; ct < 4; ct++)
                #pragma unroll
                for (int j = 0; j < 4; j++) {
                    float pv = __expf(sc[ct][j] - m[j]);
                    rs[j] += pv;
                    Ps[w][(lg * 4 + j) * 72 + ct * 16 + lr] = f2bf(pv);
                }
            #pragma unroll
            for (int j = 0; j < 4; j++) {
                rs[j] += __shfl_xor(rs[j], 1);
                rs[j] += __shfl_xor(rs[j], 2);
                rs[j] += __shfl_xor(rs[j], 4);
                rs[j] += __shfl_xor(rs[j], 8);
                lden[j] = lden[j] * f[j] + rs[j];
            }
            #pragma unroll
            for (int dt = 0; dt < 4; dt++)
                #pragma unroll
                for (int j = 0; j < 4; j++)
                    o[dt][j] *= f[j];
            #pragma unroll
            for (int ks = 0; ks < 2; ks++) {
                bf16x8 pa = *(const bf16x8*)(&Ps[w][lr * 72 + ks * 32 + lg * 8]);
                __builtin_amdgcn_s_setprio(1);
                #pragma unroll
                for (int dt = 0; dt < 4; dt++) {
                    bf16x8 vb = *(const bf16x8*)(&VT[p][(dt * 16 + lr) * 72 + ks * 32 + lg * 8]);
                    o[dt] = __builtin_amdgcn_mfma_f32_16x16x32_bf16(pa, vb, o[dt], 0, 0, 0);
                }
                __builtin_amdgcn_s_setprio(0);
            }
        }
        __syncthreads();
        if (vnext) {
            #pragma unroll
            for (int g = 0; g < 4; g++)
                #pragma unroll
                for (int e = 0; e < 8; e++)
                    VT[pp][(vdh0 + g * 16 + e) * 72 + vkey] = (u16)vr[g][e];
        }
        __syncthreads();
    }

    float* mg = (float*)&Ks[0][0][0];
    if (p == 1) {
        int base = (rh * 64 + lane) * 24;
        #pragma unroll
        for (int dt = 0; dt < 4; dt++)
            #pragma unroll
            for (int j = 0; j < 4; j++)
                mg[base + dt * 4 + j] = o[dt][j];
        #pragma unroll
        for (int j = 0; j < 4; j++) { mg[base + 16 + j] = m[j]; mg[base + 20 + j] = lden[j]; }
    }
    __syncthreads();
    if (p == 0) {
        int base = (rh * 64 + lane) * 24;
        #pragma unroll
        for (int j = 0; j < 4; j++) {
            float m1 = mg[base + 16 + j];
            float l1 = mg[base + 20 + j];
            float mf = fmaxf(m[j], m1);
            float e0 = __expf(m[j] - mf), e1 = __expf(m1 - mf);
            float inv = 1.0f / (lden[j] * e0 + l1 * e1);
            int qrow = qt * 32 + rh * 16 + lg * 4 + j;
            size_t ybase = ((size_t)(bidx * T_ + qrow)) * D_ + h * DH_;
            #pragma unroll
            for (int dt = 0; dt < 4; dt++) {
                float of = (o[dt][j] * e0 + mg[base + dt * 4 + j] * e1) * inv;
                y[ybase + dt * 16 + lr] = f2bf(of);
            }
        }
    }
}

// ================= head GEMM: col-major-within-XCD mapping, counted vmcnt, nt stores ====
__global__ __launch_bounds__(256) void head_gemm(
    const u16* __restrict__ A, const u16* __restrict__ BT,
    const float* __restrict__ bias, float* __restrict__ C,
    int M, int N, int K)
{
    __shared__ u16 As[2][128*64];
    __shared__ u16 Bs[2][128*64];
    int tid = threadIdx.x;
    int lane = tid & 63, w = tid >> 6;
    int lr = lane & 15, lg = lane >> 4;
    int wm = w >> 1, wn = w & 1;

    int orig = blockIdx.y * gridDim.x + blockIdx.x;   // 8000 blocks
    int bid = xcd_swizzle(orig, 8000);
    int col0 = (bid >> 5) * 128;
    int row0 = (bid & 31) * 128;

    f32x4 acc[4][4] = {};

    auto stage = [&](int buf, int k0) {
        #pragma unroll
        for (int i = 0; i < 4; i++) {
            int o16 = tid + i * 256;
            int r = o16 >> 3;
            int sw = ((o16 & 7) << 4) ^ ((r & 7) << 4);
            GLOAD16(A + (size_t)(row0 + r) * K + k0 + (sw >> 1), &As[buf][o16 * 8]);
            GLOAD16(BT + (size_t)(col0 + r) * K + k0 + (sw >> 1), &Bs[buf][o16 * 8]);
        }
    };

    stage(0, 0);
    int nk = K >> 6;
    for (int t = 0; t < nk; t++) {
        int cur = t & 1;
        BAR_A();
        if (t + 1 < nk) { stage(cur ^ 1, (t + 1) << 6); WAITB(8); }
        else            { WAITB(0); }
        #pragma unroll
        for (int ks = 0; ks < 2; ks++) {
            bf16x8 af[4], bfr[4];
            #pragma unroll
            for (int mi = 0; mi < 4; mi++) {
                int rr = wm * 64 + mi * 16 + lr;
                af[mi] = *(const bf16x8*)(&As[cur][rr * 64 + (((ks * 64 + lg * 16) ^ ((rr & 7) << 4)) >> 1)]);
            }
            #pragma unroll
            for (int ni = 0; ni < 4; ni++) {
                int rr = wn * 64 + ni * 16 + lr;
                bfr[ni] = *(const bf16x8*)(&Bs[cur][rr * 64 + (((ks * 64 + lg * 16) ^ ((rr & 7) << 4)) >> 1)]);
            }
            __builtin_amdgcn_s_setprio(1);
            #pragma unroll
            for (int mi = 0; mi < 4; mi++)
                #pragma unroll
                for (int ni = 0; ni < 4; ni++)
                    acc[mi][ni] = __builtin_amdgcn_mfma_f32_16x16x32_bf16(af[mi], bfr[ni], acc[mi][ni], 0, 0, 0);
            __builtin_amdgcn_s_setprio(0);
        }
    }

    #pragma unroll
    for (int mi = 0; mi < 4; mi++)
        #pragma unroll
        for (int ni = 0; ni < 4; ni++)
            #pragma unroll
            for (int j = 0; j < 4; j++) {
                int row = row0 + wm * 64 + mi * 16 + lg * 4 + j;
                int col = col0 + wn * 64 + ni * 16 + lr;
                __builtin_nontemporal_store(acc[mi][ni][j] + bias[col], &C[(size_t)row * N + col]);
            }
}

// ================= host launch =================
extern "C" void kernel_launch(void* const* d_in, const int* in_sizes, int n_in,
                              void* d_out, int out_size, void* d_ws, size_t ws_size,
                              hipStream_t stream)
{
    const int*   idx  = (const int*)d_in[0];
    const float* tok  = (const float*)d_in[1];
    const float* pos  = (const float*)d_in[2];
    const float* Wq   = (const float*)d_in[3];
    const float* bq   = (const float*)d_in[4];
    const float* Wk   = (const float*)d_in[5];
    const float* bk   = (const float*)d_in[6];
    const float* Wv   = (const float*)d_in[7];
    const float* bv   = (const float*)d_in[8];
    const float* Wo   = (const float*)d_in[9];
    const float* bo   = (const float*)d_in[10];
    const float* ln1g = (const float*)d_in[11];
    const float* ln1b = (const float*)d_in[12];
    const float* W1   = (const float*)d_in[13];
    const float* b1   = (const float*)d_in[14];
    const float* W2   = (const float*)d_in[15];
    const float* b2   = (const float*)d_in[16];
    const float* ln2g = (const float*)d_in[17];
    const float* ln2b = (const float*)d_in[18];
    const float* lnfg = (const float*)d_in[19];
    const float* lnfb = (const float*)d_in[20];
    const float* hW   = (const float*)d_in[21];
    const float* hb   = (const float*)d_in[22];

    char* p = (char*)d_ws;
    float* x     = (float*)p;           p += (size_t)NTOK * D_ * 4;
    u16* hbuf    = (u16*)p;             p += (size_t)NTOK * D_ * 2;
    u16* qkvbuf  = (u16*)p;             p += (size_t)3 * NTOK * D_ * 2;
    u16* ybuf    = (u16*)p;             p += (size_t)NTOK * D_ * 2;
    u16* ff      = (u16*)p;             p += (size_t)NTOK * DF_ * 2;
    u16* WqkvT   = (u16*)p;             p += (size_t)L_ * 768 * D_ * 2;
    u16* WoT     = (u16*)p;             p += (size_t)L_ * D_ * D_ * 2;
    u16* W1T     = (u16*)p;             p += (size_t)L_ * D_ * DF_ * 2;
    u16* W2T     = (u16*)p;             p += (size_t)L_ * DF_ * D_ * 2;
    u16* hWT     = (u16*)p;             p += (size_t)V_ * D_ * 2;

    u16* qbuf = qkvbuf;
    u16* kbuf = qkvbuf + (size_t)NTOK * D_;
    u16* vbuf = qkvbuf + (size_t)2 * NTOK * D_;

    prep_kernel<<<5536, 256, 0, stream>>>(Wq, Wk, Wv, Wo, W1, W2, hW,
                                          WqkvT, WoT, W1T, W2T, hWT);

    embed_qkv_kernel<<<256, 256, 0, stream>>>(idx, tok, pos, ln1g, ln1b,
                                              WqkvT, bq, bk, bv, x, qkvbuf);

    dim3 gAttn(64, 8);                   // 512 balanced blocks
    dim3 gFF1(DF_ / 64, NTOK / 64);      // (16, 64)
    for (int l = 0; l < L_; l++) {
        attn_kernel<<<gAttn, 256, 0, stream>>>(qbuf, kbuf, vbuf, ybuf);
        wo_ln_kernel<<<256, 256, 0, stream>>>(ybuf, WoT + (size_t)l * 65536, bo + l * D_,
                                              ln2g + l * D_, ln2b + l * D_, x, hbuf);
        ff1_kernel<<<gFF1, 256, 0, stream>>>(hbuf, W1T + (size_t)l * 262144, b1 + l * DF_, ff);
        if (l < L_ - 1) {
            ff2qkv_kernel<false><<<256, 256, 0, stream>>>(
                ff, W2T + (size_t)l * 262144, b2 + l * D_,
                ln1g + (l + 1) * D_, ln1b + (l + 1) * D_,
                WqkvT + (size_t)(l + 1) * 196608,
                bq + (l + 1) * D_, bk + (l + 1) * D_, bv + (l + 1) * D_,
                x, nullptr, qkvbuf);
        } else {
            ff2qkv_kernel<true><<<256, 256, 0, stream>>>(
                ff, W2T + (size_t)l * 262144, b2 + l * D_,
                lnfg, lnfb,
                nullptr, nullptr, nullptr, nullptr,
                x, hbuf, nullptr);
        }
    }

    dim3 gHead(V_ / 128, NTOK / 128);    // (250, 32)
    head_gemm<<<gHead, 256, 0, stream>>>(hbuf, hWT, hb, (float*)d_out, NTOK, V_, D_);
}

// Round 12
// 478.998 us; speedup vs baseline: 1.3736x; 1.0465x over previous
//
#include <hip/hip_runtime.h>
#include <hip/hip_bf16.h>
#include <math.h>

#define V_   32000
#define L_   4
#define H_   4
#define D_   256
#define DF_  1024
#define B_   2
#define T_   2048
#define DH_  64
#define NTOK (B_*T_)   // 4096

typedef __attribute__((ext_vector_type(8))) short bf16x8;
typedef __attribute__((ext_vector_type(4))) float f32x4;
typedef unsigned short u16;

#define GLOAD16(gsrc, ldst) \
  __builtin_amdgcn_global_load_lds((const __attribute__((address_space(1))) void*)(gsrc), \
                                   (__attribute__((address_space(3))) void*)(ldst), 16, 0, 0)

// counted-vmcnt stage boundary (T4): barrier_A -> issue -> vmcnt(N)+lgkm -> barrier_B
#define BAR_A()   asm volatile("s_barrier" ::: "memory")
#define WAITB(N)  do { asm volatile("s_waitcnt vmcnt(" #N ") lgkmcnt(0)" ::: "memory"); \
                       asm volatile("s_barrier" ::: "memory"); } while (0)

__device__ __forceinline__ u16 f2bf(float f) {
    unsigned int u = __builtin_bit_cast(unsigned int, f);
    u = (u + 0x7fff + ((u >> 16) & 1)) >> 16;   // RNE
    return (u16)u;
}

__device__ __forceinline__ int xcd_swizzle(int orig, int nwg) {
    return ((nwg & 7) == 0) ? ((orig & 7) * (nwg >> 3) + (orig >> 3)) : orig;
}

// ================= prep: weight transposes f32[K,N] -> bf16[N,K], 64k x 32n tiles =====
__global__ __launch_bounds__(256) void prep_kernel(
    const float* __restrict__ Wq, const float* __restrict__ Wk,
    const float* __restrict__ Wv, const float* __restrict__ Wo,
    const float* __restrict__ W1, const float* __restrict__ W2,
    const float* __restrict__ hW,
    u16* __restrict__ WqkvT, u16* __restrict__ WoT,
    u16* __restrict__ W1T, u16* __restrict__ W2T, u16* __restrict__ hWT)
{
    int b = blockIdx.x;
    const float* src; u16* dst; int K, N, k0, n0;
    if (b < 512) {
        int m = b >> 5, t = b & 31;
        int wt = m & 3, l = m >> 2;
        K = 256; N = 256;
        src = (wt == 0 ? Wq : wt == 1 ? Wk : wt == 2 ? Wv : Wo) + (size_t)l * 65536;
        dst = (wt < 3) ? WqkvT + (size_t)l * 196608 + (size_t)wt * 65536
                       : WoT + (size_t)l * 65536;
        k0 = (t >> 3) * 64; n0 = (t & 7) * 32;
    } else if (b < 1024) {
        int bb = b - 512; int l = bb >> 7, t = bb & 127;
        K = 256; N = 1024;
        src = W1 + (size_t)l * 262144; dst = W1T + (size_t)l * 262144;
        k0 = (t >> 5) * 64; n0 = (t & 31) * 32;
    } else if (b < 1536) {
        int bb = b - 1024; int l = bb >> 7, t = bb & 127;
        K = 1024; N = 256;
        src = W2 + (size_t)l * 262144; dst = W2T + (size_t)l * 262144;
        k0 = (t >> 3) * 64; n0 = (t & 7) * 32;
    } else {
        int bb = b - 1536;
        K = 256; N = 32000;
        src = hW; dst = hWT;
        k0 = (bb / 1000) * 64; n0 = (bb % 1000) * 32;
    }
    __shared__ float tile[64][33];
    int tid = threadIdx.x;
    int tc = tid & 31, tr = tid >> 5;
    #pragma unroll
    for (int i = 0; i < 8; i++)
        tile[tr + i*8][tc] = src[(size_t)(k0 + tr + i*8) * N + n0 + tc];
    __syncthreads();
    int kc = tid & 63, nr = tid >> 6;
    #pragma unroll
    for (int i = 0; i < 8; i++)
        dst[(size_t)(n0 + nr + i*4) * K + k0 + kc] = f2bf(tile[kc][nr + i*4]);
}

// ================= embed + LN1(l0) + QKV(l0): 256 blocks x 256t, 16 rows/block =========
__global__ __launch_bounds__(256) void embed_qkv_kernel(
    const int* __restrict__ idx, const float* __restrict__ tok, const float* __restrict__ pos,
    const float* __restrict__ g, const float* __restrict__ bta,
    const u16* __restrict__ WqkvT0,
    const float* __restrict__ bq, const float* __restrict__ bk, const float* __restrict__ bv,
    float* __restrict__ x, u16* __restrict__ qkv)
{
    __shared__ u16 Bs[2][256*64];
    __shared__ u16 hS[16][264];

    int tid = threadIdx.x;
    int lane = tid & 63, w = tid >> 6;
    int lr = lane & 15, lg = lane >> 4;
    int bid = xcd_swizzle(blockIdx.x, 256);
    int row0 = bid * 16;

    {
        int grow = tid >> 4;
        int gcol = (tid & 15) * 16;
        int n = row0 + grow;
        int t = n & (T_ - 1);
        int id = idx[n];
        float vv[16];
        #pragma unroll
        for (int i = 0; i < 4; i++) {
            float4 a = *(const float4*)(tok + (size_t)id * D_ + gcol + i * 4);
            float4 b = *(const float4*)(pos + (size_t)t * D_ + gcol + i * 4);
            vv[i*4+0] = a.x + b.x; vv[i*4+1] = a.y + b.y;
            vv[i*4+2] = a.z + b.z; vv[i*4+3] = a.w + b.w;
        }
        float s = 0.f, q = 0.f;
        #pragma unroll
        for (int i = 0; i < 16; i++) { s += vv[i]; q += vv[i]*vv[i]; }
        #pragma unroll
        for (int o = 1; o <= 8; o <<= 1) { s += __shfl_xor(s, o); q += __shfl_xor(q, o); }
        float mu = s * (1.0f / D_);
        float var = q * (1.0f / D_) - mu * mu;
        float ri = rsqrtf(var + 1e-5f);
        #pragma unroll
        for (int i = 0; i < 16; i++) {
            x[(size_t)n * D_ + gcol + i] = vv[i];
            hS[grow][gcol + i] = f2bf((vv[i] - mu) * ri * g[gcol + i] + bta[gcol + i]);
        }
    }

    auto stageQ = [&](int buf, int u) {
        const u16* BT = WqkvT0 + (size_t)(u >> 2) * 65536;
        int k0 = (u & 3) * 64;
        #pragma unroll
        for (int i = 0; i < 8; i++) {
            int o16 = tid + i * 256;
            int r = o16 >> 3;
            int sw = ((o16 & 7) << 4) ^ ((r & 7) << 4);
            GLOAD16(BT + (size_t)r * 256 + k0 + (sw >> 1), &Bs[buf][o16 * 8]);
        }
    };
    auto afH = [&](int t, int ks) -> bf16x8 {
        return *(const bf16x8*)(&hS[lr][(t * 128 + ks * 64 + lg * 16) >> 1]);
    };
    auto bfr = [&](int buf, int ni, int ks) -> bf16x8 {
        int rr = w * 64 + ni * 16 + lr;
        return *(const bf16x8*)(&Bs[buf][rr * 64 + (((ks * 64 + lg * 16) ^ ((rr & 7) << 4)) >> 1)]);
    };

    stageQ(0, 0);
    f32x4 acc[4] = {};
    for (int u = 0; u < 12; u++) {
        BAR_A();
        if (u + 1 < 12) { stageQ((u + 1) & 1, u + 1); WAITB(8); }
        else            { WAITB(0); }
        int t = u & 3;
        #pragma unroll
        for (int ks = 0; ks < 2; ks++) {
            bf16x8 a = afH(t, ks);
            __builtin_amdgcn_s_setprio(1);
            #pragma unroll
            for (int ni = 0; ni < 4; ni++)
                acc[ni] = __builtin_amdgcn_mfma_f32_16x16x32_bf16(a, bfr(u & 1, ni, ks), acc[ni], 0, 0, 0);
            __builtin_amdgcn_s_setprio(0);
        }
        if (t == 3) {
            int sel = u >> 2;
            const float* bp = sel == 0 ? bq : sel == 1 ? bk : bv;
            #pragma unroll
            for (int ni = 0; ni < 4; ni++) {
                #pragma unroll
                for (int j = 0; j < 4; j++) {
                    int row = row0 + lg * 4 + j;
                    int cc = w * 64 + ni * 16 + lr;
                    float v = acc[ni][j] + bp[cc];
                    int bb = row >> 11, tt = row & (T_ - 1);
                    int hh = cc >> 6, dh = cc & 63;
                    qkv[(size_t)sel * NTOK * D_ +
                        ((((size_t)bb * H_ + hh) * T_) + tt) * DH_ + dh] = f2bf(v);
                }
                acc[ni] = (f32x4){0.f, 0.f, 0.f, 0.f};
            }
        }
    }
}

// ================= Wo + residual + LN2: 256 blocks x 256t, 16 rows/block ==========
__global__ __launch_bounds__(256) void wo_ln_kernel(
    const u16* __restrict__ ybuf, const u16* __restrict__ WoT, const float* __restrict__ bo,
    const float* __restrict__ ln2g, const float* __restrict__ ln2b,
    float* __restrict__ x, u16* __restrict__ hbuf)
{
    __shared__ u16 As[2][16*64];
    __shared__ u16 Bs[2][256*64];
    __shared__ float sred[4][16], qred[4][16];

    int tid = threadIdx.x;
    int lane = tid & 63, w = tid >> 6;
    int lr = lane & 15, lg = lane >> 4;
    int bid = xcd_swizzle(blockIdx.x, 256);
    int row0 = bid * 16;

    // T14: hoist residual x reads before the K-loop (latency hidden under MFMA)
    float xv[4][4];
    #pragma unroll
    for (int ni = 0; ni < 4; ni++)
        #pragma unroll
        for (int j = 0; j < 4; j++)
            xv[ni][j] = x[(size_t)(row0 + lg * 4 + j) * D_ + w * 64 + ni * 16 + lr];

    auto stage = [&](int buf, int k0) {
        #pragma unroll
        for (int i = 0; i < 8; i++) {
            int o16 = tid + i * 256;
            int r = o16 >> 3;
            int sw = ((o16 & 7) << 4) ^ ((r & 7) << 4);
            GLOAD16(WoT + (size_t)r * 256 + k0 + (sw >> 1), &Bs[buf][o16 * 8]);
        }
        if (tid < 128) {
            int r = tid >> 3;
            int sw = ((tid & 7) << 4) ^ ((r & 7) << 4);
            GLOAD16(ybuf + (size_t)(row0 + r) * 256 + k0 + (sw >> 1), &As[buf][tid * 8]);
        }
    };
    auto afA = [&](int buf, int ks) -> bf16x8 {
        return *(const bf16x8*)(&As[buf][lr * 64 + (((ks * 64 + lg * 16) ^ ((lr & 7) << 4)) >> 1)]);
    };
    auto bfr = [&](int buf, int ni, int ks) -> bf16x8 {
        int rr = w * 64 + ni * 16 + lr;
        return *(const bf16x8*)(&Bs[buf][rr * 64 + (((ks * 64 + lg * 16) ^ ((rr & 7) << 4)) >> 1)]);
    };

    stage(0, 0);
    f32x4 acc[4] = {};
    for (int t = 0; t < 4; t++) {
        BAR_A();
        if (t + 1 < 4) { stage((t + 1) & 1, (t + 1) * 64); WAITB(8); }
        else           { WAITB(0); }
        #pragma unroll
        for (int ks = 0; ks < 2; ks++) {
            bf16x8 a = afA(t & 1, ks);
            __builtin_amdgcn_s_setprio(1);
            #pragma unroll
            for (int ni = 0; ni < 4; ni++)
                acc[ni] = __builtin_amdgcn_mfma_f32_16x16x32_bf16(a, bfr(t & 1, ni, ks), acc[ni], 0, 0, 0);
            __builtin_amdgcn_s_setprio(0);
        }
    }

    float vals[4][4];
    float rs[4] = {0,0,0,0}, rq[4] = {0,0,0,0};
    #pragma unroll
    for (int ni = 0; ni < 4; ni++)
        #pragma unroll
        for (int j = 0; j < 4; j++) {
            int row = row0 + lg * 4 + j;
            int col = w * 64 + ni * 16 + lr;
            float v = acc[ni][j] + bo[col] + xv[ni][j];
            x[(size_t)row * D_ + col] = v;
            vals[ni][j] = v;
            rs[j] += v; rq[j] += v * v;
        }
    #pragma unroll
    for (int j = 0; j < 4; j++)
        #pragma unroll
        for (int o = 1; o <= 8; o <<= 1) { rs[j] += __shfl_xor(rs[j], o); rq[j] += __shfl_xor(rq[j], o); }
    if (lr == 0)
        #pragma unroll
        for (int j = 0; j < 4; j++) { sred[w][lg*4 + j] = rs[j]; qred[w][lg*4 + j] = rq[j]; }
    __syncthreads();
    #pragma unroll
    for (int j = 0; j < 4; j++) {
        int r = lg * 4 + j;
        float mu = (sred[0][r] + sred[1][r] + sred[2][r] + sred[3][r]) * (1.0f / D_);
        float var = (qred[0][r] + qred[1][r] + qred[2][r] + qred[3][r]) * (1.0f / D_) - mu * mu;
        float ri = rsqrtf(var + 1e-5f);
        int row = row0 + r;
        #pragma unroll
        for (int ni = 0; ni < 4; ni++) {
            int col = w * 64 + ni * 16 + lr;
            hbuf[(size_t)row * D_ + col] = f2bf((vals[ni][j] - mu) * ri * ln2g[col] + ln2b[col]);
        }
    }
}

// ================= FF1 + GELU: 64x64 tiles, 1024 blocks, triple-buffered 1-barrier ======
__global__ __launch_bounds__(256) void ff1_kernel(
    const u16* __restrict__ A, const u16* __restrict__ BT,
    const float* __restrict__ bias, u16* __restrict__ C)
{
    __shared__ u16 As[3][64*64];
    __shared__ u16 Bs[3][64*64];
    int tid = threadIdx.x;
    int lane = tid & 63, w = tid >> 6;
    int lr = lane & 15, lg = lane >> 4;
    int wm = w >> 1, wn = w & 1;

    int gx = gridDim.x;
    int nwg = gx * gridDim.y;
    int orig = blockIdx.y * gx + blockIdx.x;
    int bid = xcd_swizzle(orig, nwg);
    int row0 = (bid / gx) * 64, col0 = (bid % gx) * 64;

    auto stage = [&](int buf, int k0) {
        #pragma unroll
        for (int i = 0; i < 2; i++) {
            int o16 = tid + i * 256;
            int r = o16 >> 3;
            int sw = ((o16 & 7) << 4) ^ ((r & 7) << 4);
            GLOAD16(A + (size_t)(row0 + r) * 256 + k0 + (sw >> 1), &As[buf][o16 * 8]);
            GLOAD16(BT + (size_t)(col0 + r) * 256 + k0 + (sw >> 1), &Bs[buf][o16 * 8]);
        }
    };

    f32x4 acc[2][2] = {};
    auto compute = [&](int buf) {
        #pragma unroll
        for (int ks = 0; ks < 2; ks++) {
            bf16x8 af[2], bfv[2];
            #pragma unroll
            for (int mi = 0; mi < 2; mi++) {
                int rr = wm * 32 + mi * 16 + lr;
                af[mi] = *(const bf16x8*)(&As[buf][rr * 64 + (((ks * 64 + lg * 16) ^ ((rr & 7) << 4)) >> 1)]);
            }
            #pragma unroll
            for (int ni = 0; ni < 2; ni++) {
                int rr = wn * 32 + ni * 16 + lr;
                bfv[ni] = *(const bf16x8*)(&Bs[buf][rr * 64 + (((ks * 64 + lg * 16) ^ ((rr & 7) << 4)) >> 1)]);
            }
            __builtin_amdgcn_s_setprio(1);
            #pragma unroll
            for (int mi = 0; mi < 2; mi++)
                #pragma unroll
                for (int ni = 0; ni < 2; ni++)
                    acc[mi][ni] = __builtin_amdgcn_mfma_f32_16x16x32_bf16(af[mi], bfv[ni], acc[mi][ni], 0, 0, 0);
            __builtin_amdgcn_s_setprio(0);
        }
    };

    // 3-buffer single-barrier pipeline: wait(stage t) -> barrier -> issue(t+2) -> compute(t)
    stage(0, 0); stage(1, 64);
    asm volatile("s_waitcnt vmcnt(4) lgkmcnt(0)" ::: "memory");
    asm volatile("s_barrier" ::: "memory");
    stage(2, 128);
    compute(0);
    asm volatile("s_waitcnt vmcnt(4) lgkmcnt(0)" ::: "memory");
    asm volatile("s_barrier" ::: "memory");
    stage(0, 192);
    compute(1);
    asm volatile("s_waitcnt vmcnt(4) lgkmcnt(0)" ::: "memory");
    asm volatile("s_barrier" ::: "memory");
    compute(2);
    asm volatile("s_waitcnt vmcnt(0) lgkmcnt(0)" ::: "memory");
    asm volatile("s_barrier" ::: "memory");
    compute(0);

    #pragma unroll
    for (int mi = 0; mi < 2; mi++)
        #pragma unroll
        for (int ni = 0; ni < 2; ni++)
            #pragma unroll
            for (int j = 0; j < 4; j++) {
                int row = row0 + wm * 32 + mi * 16 + lg * 4 + j;
                int col = col0 + wn * 32 + ni * 16 + lr;
                float v = acc[mi][ni][j] + bias[col];
                v = 0.5f * v * (1.0f + erff(v * 0.70710678118f));
                C[(size_t)row * DF_ + col] = f2bf(v);
            }
}

// ================= FF2 + residual + LN(next) + QKV(next): 256 blocks, 16 rows =========
template<bool LAST>
__global__ __launch_bounds__(256) void ff2qkv_kernel(
    const u16* __restrict__ ff, const u16* __restrict__ W2T, const float* __restrict__ b2,
    const float* __restrict__ lng, const float* __restrict__ lnb,
    const u16* __restrict__ WqkvT,
    const float* __restrict__ bq, const float* __restrict__ bk, const float* __restrict__ bv,
    float* __restrict__ x, u16* __restrict__ hout, u16* __restrict__ qkv)
{
    __shared__ u16 As[2][16*64];
    __shared__ u16 Bs[2][256*64];
    __shared__ u16 hS[16][264];
    __shared__ float sred[4][16], qred[4][16];

    int tid = threadIdx.x;
    int lane = tid & 63, w = tid >> 6;
    int lr = lane & 15, lg = lane >> 4;
    int bid = xcd_swizzle(blockIdx.x, 256);
    int row0 = bid * 16;

    // T14: hoist residual x reads
    float xv[4][4];
    #pragma unroll
    for (int ni = 0; ni < 4; ni++)
        #pragma unroll
        for (int j = 0; j < 4; j++)
            xv[ni][j] = x[(size_t)(row0 + lg * 4 + j) * D_ + w * 64 + ni * 16 + lr];

    auto stageB = [&](int buf, const u16* BT, int K, int k0) {
        #pragma unroll
        for (int i = 0; i < 8; i++) {
            int o16 = tid + i * 256;
            int r = o16 >> 3;
            int sw = ((o16 & 7) << 4) ^ ((r & 7) << 4);
            GLOAD16(BT + (size_t)r * K + k0 + (sw >> 1), &Bs[buf][o16 * 8]);
        }
    };
    auto stageA = [&](int buf, int k0) {
        if (tid < 128) {
            int r = tid >> 3;
            int sw = ((tid & 7) << 4) ^ ((r & 7) << 4);
            GLOAD16(ff + (size_t)(row0 + r) * DF_ + k0 + (sw >> 1), &As[buf][tid * 8]);
        }
    };
    auto prefetch = [&](int u) {
        if (u < 16) { stageA(u & 1, u * 64); stageB(u & 1, W2T, 1024, u * 64); }
        else if (!LAST && u < 28) {
            int v = u - 16;
            stageB(u & 1, WqkvT + (size_t)(v >> 2) * 65536, 256, (v & 3) * 64);
        }
    };
    auto afA = [&](int buf, int ks) -> bf16x8 {
        return *(const bf16x8*)(&As[buf][lr * 64 + (((ks * 64 + lg * 16) ^ ((lr & 7) << 4)) >> 1)]);
    };
    auto afH = [&](int t, int ks) -> bf16x8 {
        return *(const bf16x8*)(&hS[lr][(t * 128 + ks * 64 + lg * 16) >> 1]);
    };
    auto bfr = [&](int buf, int ni, int ks) -> bf16x8 {
        int rr = w * 64 + ni * 16 + lr;
        return *(const bf16x8*)(&Bs[buf][rr * 64 + (((ks * 64 + lg * 16) ^ ((rr & 7) << 4)) >> 1)]);
    };

    prefetch(0);
    f32x4 acc[4] = {};
    for (int u = 0; u < 16; u++) {
        BAR_A();
        prefetch(u + 1);
        WAITB(8);
        #pragma unroll
        for (int ks = 0; ks < 2; ks++) {
            bf16x8 a = afA(u & 1, ks);
            __builtin_amdgcn_s_setprio(1);
            #pragma unroll
            for (int ni = 0; ni < 4; ni++)
                acc[ni] = __builtin_amdgcn_mfma_f32_16x16x32_bf16(a, bfr(u & 1, ni, ks), acc[ni], 0, 0, 0);
            __builtin_amdgcn_s_setprio(0);
        }
    }

    {
        float vals[4][4];
        float rs[4] = {0,0,0,0}, rq[4] = {0,0,0,0};
        #pragma unroll
        for (int ni = 0; ni < 4; ni++)
            #pragma unroll
            for (int j = 0; j < 4; j++) {
                int row = row0 + lg * 4 + j;
                int col = w * 64 + ni * 16 + lr;
                float v = acc[ni][j] + b2[col] + xv[ni][j];
                x[(size_t)row * D_ + col] = v;
                vals[ni][j] = v;
                rs[j] += v; rq[j] += v * v;
            }
        #pragma unroll
        for (int j = 0; j < 4; j++)
            #pragma unroll
            for (int o = 1; o <= 8; o <<= 1) { rs[j] += __shfl_xor(rs[j], o); rq[j] += __shfl_xor(rq[j], o); }
        if (lr == 0)
            #pragma unroll
            for (int j = 0; j < 4; j++) { sred[w][lg*4 + j] = rs[j]; qred[w][lg*4 + j] = rq[j]; }
        __syncthreads();
        #pragma unroll
        for (int j = 0; j < 4; j++) {
            int r = lg * 4 + j;
            float mu = (sred[0][r] + sred[1][r] + sred[2][r] + sred[3][r]) * (1.0f / D_);
            float var = (qred[0][r] + qred[1][r] + qred[2][r] + qred[3][r]) * (1.0f / D_) - mu * mu;
            float ri = rsqrtf(var + 1e-5f);
            #pragma unroll
            for (int ni = 0; ni < 4; ni++) {
                int col = w * 64 + ni * 16 + lr;
                float hv = (vals[ni][j] - mu) * ri * lng[col] + lnb[col];
                if (LAST) hout[(size_t)(row0 + r) * D_ + col] = f2bf(hv);
                else      hS[r][col] = f2bf(hv);
            }
        }
    }

    if constexpr (!LAST) {
        __syncthreads();
        f32x4 accT[4] = {};
        for (int v = 0; v < 12; v++) {
            BAR_A();
            if (v + 1 < 12) { prefetch(16 + v + 1); WAITB(8); }
            else            { WAITB(0); }
            int t = v & 3;
            #pragma unroll
            for (int ks = 0; ks < 2; ks++) {
                bf16x8 a = afH(t, ks);
                __builtin_amdgcn_s_setprio(1);
                #pragma unroll
                for (int ni = 0; ni < 4; ni++)
                    accT[ni] = __builtin_amdgcn_mfma_f32_16x16x32_bf16(a, bfr(v & 1, ni, ks), accT[ni], 0, 0, 0);
                __builtin_amdgcn_s_setprio(0);
            }
            if (t == 3) {
                int sel = v >> 2;
                const float* bp = sel == 0 ? bq : sel == 1 ? bk : bv;
                #pragma unroll
                for (int ni = 0; ni < 4; ni++) {
                    #pragma unroll
                    for (int j = 0; j < 4; j++) {
                        int row = row0 + lg * 4 + j;
                        int cc = w * 64 + ni * 16 + lr;
                        float val = accT[ni][j] + bp[cc];
                        int bb = row >> 11, tt = row & (T_ - 1);
                        int hh = cc >> 6, dh = cc & 63;
                        qkv[(size_t)sel * NTOK * D_ +
                            ((((size_t)bb * H_ + hh) * T_) + tt) * DH_ + dh] = f2bf(val);
                    }
                    accT[ni] = (f32x4){0.f, 0.f, 0.f, 0.f};
                }
            }
        }
    }
}

// ================= attention: QBLK=32, key-parity split over wave pairs, balanced =====
__global__ __launch_bounds__(256) void attn_kernel(
    const u16* __restrict__ q, const u16* __restrict__ k,
    const u16* __restrict__ v, u16* __restrict__ y)
{
    int linear = blockIdx.y * gridDim.x + blockIdx.x;   // 0..511
    int half = linear >> 8, rem = linear & 255;
    int qt_raw = rem & 63;
    int qt = half ? 63 - qt_raw : qt_raw;
    int bh = (rem >> 6) + half * 4;
    int bidx = bh >> 2, h = bh & 3;
    const u16* qp = q + (size_t)bh * T_ * DH_;
    const u16* kp = k + (size_t)bh * T_ * DH_;
    const u16* vp = v + (size_t)bh * T_ * DH_;

    int nch = (qt + 2) >> 1;

    __shared__ u16 Qs[32*64];
    __shared__ u16 Ks[2][2][64*64];
    __shared__ u16 VT[2][64*72];
    __shared__ u16 Ps[4][16*72];

    int tid = threadIdx.x;
    int lane = tid & 63, w = tid >> 6;
    int lr = lane & 15, lg = lane >> 4;
    int p = w >> 1;
    int rh = w & 1;
    int cnt0 = (nch + 1) >> 1, cnt1 = nch >> 1;
    int mycnt = p ? cnt1 : cnt0;
    int maxit = cnt0;

    int pp = tid >> 7;
    int ppcnt = pp ? cnt1 : cnt0;
    int vkey = tid & 63;
    int vdh0 = ((tid >> 6) & 1) * 8;

    {
        int o16 = tid, r = o16 >> 3;
        int sw = ((o16 & 7) << 4) ^ ((r & 7) << 4);
        GLOAD16(qp + (size_t)(qt * 32 + r) * DH_ + (sw >> 1), &Qs[o16 * 8]);
    }
    #pragma unroll
    for (int pr = 0; pr < 2; pr++) {
        int c = min(pr, nch - 1);
        #pragma unroll
        for (int i = 0; i < 2; i++) {
            int o16 = tid + i * 256, r = o16 >> 3;
            int sw = ((o16 & 7) << 4) ^ ((r & 7) << 4);
            GLOAD16(kp + (size_t)(c * 64 + r) * DH_ + (sw >> 1), &Ks[0][pr][o16 * 8]);
        }
    }
    bf16x8 vr[4];
    {
        int c = min(pp, nch - 1);
        #pragma unroll
        for (int g = 0; g < 4; g++)
            vr[g] = *(const bf16x8*)(vp + (size_t)(c * 64 + vkey) * DH_ + vdh0 + g * 16);
    }
    __syncthreads();
    #pragma unroll
    for (int g = 0; g < 4; g++)
        #pragma unroll
        for (int e = 0; e < 8; e++)
            VT[pp][(vdh0 + g * 16 + e) * 72 + vkey] = (u16)vr[g][e];
    bf16x8 qa[2];
    #pragma unroll
    for (int ks = 0; ks < 2; ks++) {
        int rr = rh * 16 + lr;
        qa[ks] = *(const bf16x8*)(Qs + rr * 64 + (((ks * 64 + lg * 16) ^ ((rr & 7) << 4)) >> 1));
    }
    __syncthreads();

    float m[4], lden[4];
    f32x4 o[4] = {};
    #pragma unroll
    for (int j = 0; j < 4; j++) { m[j] = -1e30f; lden[j] = 0.0f; }

    for (int it = 0; it < maxit; it++) {
        int cur = it & 1;
        if (it + 1 < maxit) {
            #pragma unroll
            for (int pr = 0; pr < 2; pr++) {
                int c = min(2 * (it + 1) + pr, nch - 1);
                #pragma unroll
                for (int i = 0; i < 2; i++) {
                    int o16 = tid + i * 256, r = o16 >> 3;
                    int sw = ((o16 & 7) << 4) ^ ((r & 7) << 4);
                    GLOAD16(kp + (size_t)(c * 64 + r) * DH_ + (sw >> 1), &Ks[cur ^ 1][pr][o16 * 8]);
                }
            }
        }
        bool vnext = (it + 1 < ppcnt);
        if (vnext) {
            int c = 2 * (it + 1) + pp;
            #pragma unroll
            for (int g = 0; g < 4; g++)
                vr[g] = *(const bf16x8*)(vp + (size_t)(c * 64 + vkey) * DH_ + vdh0 + g * 16);
        }

        bool act = (it < mycnt);
        if (act) {
            int myc = 2 * it + p;
            f32x4 sc[4];
            #pragma unroll
            for (int ct = 0; ct < 4; ct++) {
                f32x4 s = {};
                __builtin_amdgcn_s_setprio(1);
                #pragma unroll
                for (int ks = 0; ks < 2; ks++) {
                    int rr = ct * 16 + lr;
                    bf16x8 kb = *(const bf16x8*)(&Ks[cur][p][rr * 64 + (((ks * 64 + lg * 16) ^ ((rr & 7) << 4)) >> 1)]);
                    s = __builtin_amdgcn_mfma_f32_16x16x32_bf16(qa[ks], kb, s, 0, 0, 0);
                }
                __builtin_amdgcn_s_setprio(0);
                sc[ct] = s;
            }
            float mloc[4];
            #pragma unroll
            for (int j = 0; j < 4; j++) mloc[j] = -1e30f;
            #pragma unroll
            for (int ct = 0; ct < 4; ct++)
                #pragma unroll
                for (int j = 0; j < 4; j++) {
                    float s = sc[ct][j] * 0.125f;
                    int key = myc * 64 + ct * 16 + lr;
                    int qrow = qt * 32 + rh * 16 + lg * 4 + j;
                    if (key > qrow) s = -1e30f;
                    sc[ct][j] = s;
                    mloc[j] = fmaxf(mloc[j], s);
                }
            #pragma unroll
            for (int j = 0; j < 4; j++) {
                mloc[j] = fmaxf(mloc[j], __shfl_xor(mloc[j], 1));
                mloc[j] = fmaxf(mloc[j], __shfl_xor(mloc[j], 2));
                mloc[j] = fmaxf(mloc[j], __shfl_xor(mloc[j], 4));
                mloc[j] = fmaxf(mloc[j], __shfl_xor(mloc[j], 8));
            }
            float f[4], rs[4];
            #pragma unroll
            for (int j = 0; j < 4; j++) {
                float nm = fmaxf(m[j], mloc[j]);
                f[j] = __expf(m[j] - nm);
                m[j] = nm;
                rs[j] = 0.0f;
            }
            #pragma unroll
            for (int ct = 0; ct < 4; ct++)
                #pragma unroll
                for (int j = 0; j < 4; j++) {
                    float pv = __expf(sc[ct][j] - m[j]);
                    rs[j] += pv;
                    Ps[w][(lg * 4 + j) * 72 + ct * 16 + lr] = f2bf(pv);
                }
            #pragma unroll
            for (int j = 0; j < 4; j++) {
                rs[j] += __shfl_xor(rs[j], 1);
                rs[j] += __shfl_xor(rs[j], 2);
                rs[j] += __shfl_xor(rs[j], 4);
                rs[j] += __shfl_xor(rs[j], 8);
                lden[j] = lden[j] * f[j] + rs[j];
            }
            #pragma unroll
            for (int dt = 0; dt < 4; dt++)
                #pragma unroll
                for (int j = 0; j < 4; j++)
                    o[dt][j] *= f[j];
            #pragma unroll
            for (int ks = 0; ks < 2; ks++) {
                bf16x8 pa = *(const bf16x8*)(&Ps[w][lr * 72 + ks * 32 + lg * 8]);
                __builtin_amdgcn_s_setprio(1);
                #pragma unroll
                for (int dt = 0; dt < 4; dt++) {
                    bf16x8 vb = *(const bf16x8*)(&VT[p][(dt * 16 + lr) * 72 + ks * 32 + lg * 8]);
                    o[dt] = __builtin_amdgcn_mfma_f32_16x16x32_bf16(pa, vb, o[dt], 0, 0, 0);
                }
                __builtin_amdgcn_s_setprio(0);
            }
        }
        __syncthreads();
        if (vnext) {
            #pragma unroll
            for (int g = 0; g < 4; g++)
                #pragma unroll
                for (int e = 0; e < 8; e++)
                    VT[pp][(vdh0 + g * 16 + e) * 72 + vkey] = (u16)vr[g][e];
        }
        __syncthreads();
    }

    float* mg = (float*)&Ks[0][0][0];
    if (p == 1) {
        int base = (rh * 64 + lane) * 24;
        #pragma unroll
        for (int dt = 0; dt < 4; dt++)
            #pragma unroll
            for (int j = 0; j < 4; j++)
                mg[base + dt * 4 + j] = o[dt][j];
        #pragma unroll
        for (int j = 0; j < 4; j++) { mg[base + 16 + j] = m[j]; mg[base + 20 + j] = lden[j]; }
    }
    __syncthreads();
    if (p == 0) {
        int base = (rh * 64 + lane) * 24;
        #pragma unroll
        for (int j = 0; j < 4; j++) {
            float m1 = mg[base + 16 + j];
            float l1 = mg[base + 20 + j];
            float mf = fmaxf(m[j], m1);
            float e0 = __expf(m[j] - mf), e1 = __expf(m1 - mf);
            float inv = 1.0f / (lden[j] * e0 + l1 * e1);
            int qrow = qt * 32 + rh * 16 + lg * 4 + j;
            size_t ybase = ((size_t)(bidx * T_ + qrow)) * D_ + h * DH_;
            #pragma unroll
            for (int dt = 0; dt < 4; dt++) {
                float of = (o[dt][j] * e0 + mg[base + dt * 4 + j] * e1) * inv;
                y[ybase + dt * 16 + lr] = f2bf(of);
            }
        }
    }
}

// ================= head GEMM: col-major-within-XCD, LDS-transposed f32x4 nt stores =====
__global__ __launch_bounds__(256) void head_gemm(
    const u16* __restrict__ A, const u16* __restrict__ BT,
    const float* __restrict__ bias, float* __restrict__ C,
    int M, int N, int K)
{
    __shared__ u16 smem[32768];   // 64 KB: As[2][8192] | Bs[2][8192]; reused as f32[128][128]
    u16* As = smem;
    u16* Bs = smem + 16384;
    int tid = threadIdx.x;
    int lane = tid & 63, w = tid >> 6;
    int lr = lane & 15, lg = lane >> 4;
    int wm = w >> 1, wn = w & 1;

    int orig = blockIdx.y * gridDim.x + blockIdx.x;   // 8000 blocks
    int bid = xcd_swizzle(orig, 8000);
    int col0 = (bid >> 5) * 128;
    int row0 = (bid & 31) * 128;

    f32x4 acc[4][4] = {};

    auto stage = [&](int buf, int k0) {
        #pragma unroll
        for (int i = 0; i < 4; i++) {
            int o16 = tid + i * 256;
            int r = o16 >> 3;
            int sw = ((o16 & 7) << 4) ^ ((r & 7) << 4);
            GLOAD16(A + (size_t)(row0 + r) * K + k0 + (sw >> 1), &As[buf * 8192 + o16 * 8]);
            GLOAD16(BT + (size_t)(col0 + r) * K + k0 + (sw >> 1), &Bs[buf * 8192 + o16 * 8]);
        }
    };

    stage(0, 0);
    int nk = K >> 6;
    for (int t = 0; t < nk; t++) {
        int cur = t & 1;
        BAR_A();
        if (t + 1 < nk) { stage(cur ^ 1, (t + 1) << 6); WAITB(8); }
        else            { WAITB(0); }
        #pragma unroll
        for (int ks = 0; ks < 2; ks++) {
            bf16x8 af[4], bfr[4];
            #pragma unroll
            for (int mi = 0; mi < 4; mi++) {
                int rr = wm * 64 + mi * 16 + lr;
                af[mi] = *(const bf16x8*)(&As[cur * 8192 + rr * 64 + (((ks * 64 + lg * 16) ^ ((rr & 7) << 4)) >> 1)]);
            }
            #pragma unroll
            for (int ni = 0; ni < 4; ni++) {
                int rr = wn * 64 + ni * 16 + lr;
                bfr[ni] = *(const bf16x8*)(&Bs[cur * 8192 + rr * 64 + (((ks * 64 + lg * 16) ^ ((rr & 7) << 4)) >> 1)]);
            }
            __builtin_amdgcn_s_setprio(1);
            #pragma unroll
            for (int mi = 0; mi < 4; mi++)
                #pragma unroll
                for (int ni = 0; ni < 4; ni++)
                    acc[mi][ni] = __builtin_amdgcn_mfma_f32_16x16x32_bf16(af[mi], bfr[ni], acc[mi][ni], 0, 0, 0);
            __builtin_amdgcn_s_setprio(0);
        }
    }

    // epilogue: transpose through LDS (reuse As/Bs), coalesced f32x4 nontemporal stores
    float* tS = (float*)smem;     // [128][128] f32, chunk-swizzled
    __syncthreads();
    #pragma unroll
    for (int mi = 0; mi < 4; mi++)
        #pragma unroll
        for (int ni = 0; ni < 4; ni++)
            #pragma unroll
            for (int j = 0; j < 4; j++) {
                int rl = wm * 64 + mi * 16 + lg * 4 + j;
                int cl = wn * 64 + ni * 16 + lr;
                int ch = (cl >> 2) ^ (rl & 7);
                tS[rl * 128 + ch * 4 + (cl & 3)] = acc[mi][ni][j] + bias[col0 + cl];
            }
    __syncthreads();
    int cc = tid & 31, r0l = (tid >> 5) * 16;
    #pragma unroll
    for (int i = 0; i < 16; i++) {
        int rl = r0l + i;
        int sch = cc ^ (rl & 7);
        f32x4 v4 = *(const f32x4*)&tS[rl * 128 + sch * 4];
        __builtin_nontemporal_store(v4, (f32x4*)&C[(size_t)(row0 + rl) * N + col0 + cc * 4]);
    }
}

// ================= host launch =================
extern "C" void kernel_launch(void* const* d_in, const int* in_sizes, int n_in,
                              void* d_out, int out_size, void* d_ws, size_t ws_size,
                              hipStream_t stream)
{
    const int*   idx  = (const int*)d_in[0];
    const float* tok  = (const float*)d_in[1];
    const float* pos  = (const float*)d_in[2];
    const float* Wq   = (const float*)d_in[3];
    const float* bq   = (const float*)d_in[4];
    const float* Wk   = (const float*)d_in[5];
    const float* bk   = (const float*)d_in[6];
    const float* Wv   = (const float*)d_in[7];
    const float* bv   = (const float*)d_in[8];
    const float* Wo   = (const float*)d_in[9];
    const float* bo   = (const float*)d_in[10];
    const float* ln1g = (const float*)d_in[11];
    const float* ln1b = (const float*)d_in[12];
    const float* W1   = (const float*)d_in[13];
    const float* b1   = (const float*)d_in[14];
    const float* W2   = (const float*)d_in[15];
    const float* b2   = (const float*)d_in[16];
    const float* ln2g = (const float*)d_in[17];
    const float* ln2b = (const float*)d_in[18];
    const float* lnfg = (const float*)d_in[19];
    const float* lnfb = (const float*)d_in[20];
    const float* hW   = (const float*)d_in[21];
    const float* hb   = (const float*)d_in[22];

    char* p = (char*)d_ws;
    float* x     = (float*)p;           p += (size_t)NTOK * D_ * 4;
    u16* hbuf    = (u16*)p;             p += (size_t)NTOK * D_ * 2;
    u16* qkvbuf  = (u16*)p;             p += (size_t)3 * NTOK * D_ * 2;
    u16* ybuf    = (u16*)p;             p += (size_t)NTOK * D_ * 2;
    u16* ff      = (u16*)p;             p += (size_t)NTOK * DF_ * 2;
    u16* WqkvT   = (u16*)p;             p += (size_t)L_ * 768 * D_ * 2;
    u16* WoT     = (u16*)p;             p += (size_t)L_ * D_ * D_ * 2;
    u16* W1T     = (u16*)p;             p += (size_t)L_ * D_ * DF_ * 2;
    u16* W2T     = (u16*)p;             p += (size_t)L_ * DF_ * D_ * 2;
    u16* hWT     = (u16*)p;             p += (size_t)V_ * D_ * 2;

    u16* qbuf = qkvbuf;
    u16* kbuf = qkvbuf + (size_t)NTOK * D_;
    u16* vbuf = qkvbuf + (size_t)2 * NTOK * D_;

    prep_kernel<<<5536, 256, 0, stream>>>(Wq, Wk, Wv, Wo, W1, W2, hW,
                                          WqkvT, WoT, W1T, W2T, hWT);

    embed_qkv_kernel<<<256, 256, 0, stream>>>(idx, tok, pos, ln1g, ln1b,
                                              WqkvT, bq, bk, bv, x, qkvbuf);

    dim3 gAttn(64, 8);                   // 512 balanced blocks
    dim3 gFF1(DF_ / 64, NTOK / 64);      // (16, 64)
    for (int l = 0; l < L_; l++) {
        attn_kernel<<<gAttn, 256, 0, stream>>>(qbuf, kbuf, vbuf, ybuf);
        wo_ln_kernel<<<256, 256, 0, stream>>>(ybuf, WoT + (size_t)l * 65536, bo + l * D_,
                                              ln2g + l * D_, ln2b + l * D_, x, hbuf);
        ff1_kernel<<<gFF1, 256, 0, stream>>>(hbuf, W1T + (size_t)l * 262144, b1 + l * DF_, ff);
        if (l < L_ - 1) {
            ff2qkv_kernel<false><<<256, 256, 0, stream>>>(
                ff, W2T + (size_t)l * 262144, b2 + l * D_,
                ln1g + (l + 1) * D_, ln1b + (l + 1) * D_,
                WqkvT + (size_t)(l + 1) * 196608,
                bq + (l + 1) * D_, bk + (l + 1) * D_, bv + (l + 1) * D_,
                x, nullptr, qkvbuf);
        } else {
            ff2qkv_kernel<true><<<256, 256, 0, stream>>>(
                ff, W2T + (size_t)l * 262144, b2 + l * D_,
                lnfg, lnfb,
                nullptr, nullptr, nullptr, nullptr,
                x, hbuf, nullptr);
        }
    }

    dim3 gHead(V_ / 128, NTOK / 128);    // (250, 32)
    head_gemm<<<gHead, 256, 0, stream>>>(hbuf, hWT, hb, (float*)d_out, NTOK, V_, D_);
}

// Round 13
// 474.071 us; speedup vs baseline: 1.3878x; 1.0104x over previous
//
#include <hip/hip_runtime.h>
#include <hip/hip_bf16.h>
#include <math.h>

#define V_   32000
#define L_   4
#define H_   4
#define D_   256
#define DF_  1024
#define B_   2
#define T_   2048
#define DH_  64
#define NTOK (B_*T_)   // 4096

typedef __attribute__((ext_vector_type(8))) short bf16x8;
typedef __attribute__((ext_vector_type(4))) float f32x4;
typedef unsigned short u16;

#define GLOAD16(gsrc, ldst) \
  __builtin_amdgcn_global_load_lds((const __attribute__((address_space(1))) void*)(gsrc), \
                                   (__attribute__((address_space(3))) void*)(ldst), 16, 0, 0)

// counted-vmcnt stage boundary (T4): barrier_A -> issue -> vmcnt(N)+lgkm -> barrier_B
#define BAR_A()   asm volatile("s_barrier" ::: "memory")
#define WAITB(N)  do { asm volatile("s_waitcnt vmcnt(" #N ") lgkmcnt(0)" ::: "memory"); \
                       asm volatile("s_barrier" ::: "memory"); } while (0)

__device__ __forceinline__ u16 f2bf(float f) {
    unsigned int u = __builtin_bit_cast(unsigned int, f);
    u = (u + 0x7fff + ((u >> 16) & 1)) >> 16;   // RNE
    return (u16)u;
}

__device__ __forceinline__ int xcd_swizzle(int orig, int nwg) {
    return ((nwg & 7) == 0) ? ((orig & 7) * (nwg >> 3) + (orig >> 3)) : orig;
}

// ================= prep: weight transposes f32[K,N] -> bf16[N,K], 64k x 32n tiles =====
__global__ __launch_bounds__(256) void prep_kernel(
    const float* __restrict__ Wq, const float* __restrict__ Wk,
    const float* __restrict__ Wv, const float* __restrict__ Wo,
    const float* __restrict__ W1, const float* __restrict__ W2,
    const float* __restrict__ hW,
    u16* __restrict__ WqkvT, u16* __restrict__ WoT,
    u16* __restrict__ W1T, u16* __restrict__ W2T, u16* __restrict__ hWT)
{
    int b = blockIdx.x;
    const float* src; u16* dst; int K, N, k0, n0;
    if (b < 512) {
        int m = b >> 5, t = b & 31;
        int wt = m & 3, l = m >> 2;
        K = 256; N = 256;
        src = (wt == 0 ? Wq : wt == 1 ? Wk : wt == 2 ? Wv : Wo) + (size_t)l * 65536;
        dst = (wt < 3) ? WqkvT + (size_t)l * 196608 + (size_t)wt * 65536
                       : WoT + (size_t)l * 65536;
        k0 = (t >> 3) * 64; n0 = (t & 7) * 32;
    } else if (b < 1024) {
        int bb = b - 512; int l = bb >> 7, t = bb & 127;
        K = 256; N = 1024;
        src = W1 + (size_t)l * 262144; dst = W1T + (size_t)l * 262144;
        k0 = (t >> 5) * 64; n0 = (t & 31) * 32;
    } else if (b < 1536) {
        int bb = b - 1024; int l = bb >> 7, t = bb & 127;
        K = 1024; N = 256;
        src = W2 + (size_t)l * 262144; dst = W2T + (size_t)l * 262144;
        k0 = (t >> 3) * 64; n0 = (t & 7) * 32;
    } else {
        int bb = b - 1536;
        K = 256; N = 32000;
        src = hW; dst = hWT;
        k0 = (bb / 1000) * 64; n0 = (bb % 1000) * 32;
    }
    __shared__ float tile[64][33];
    int tid = threadIdx.x;
    int tc = tid & 31, tr = tid >> 5;
    #pragma unroll
    for (int i = 0; i < 8; i++)
        tile[tr + i*8][tc] = src[(size_t)(k0 + tr + i*8) * N + n0 + tc];
    __syncthreads();
    int kc = tid & 63, nr = tid >> 6;
    #pragma unroll
    for (int i = 0; i < 8; i++)
        dst[(size_t)(n0 + nr + i*4) * K + k0 + kc] = f2bf(tile[kc][nr + i*4]);
}

// ================= embed + LN1(l0) + QKV(l0): 256 blocks x 256t, 16 rows/block =========
__global__ __launch_bounds__(256) void embed_qkv_kernel(
    const int* __restrict__ idx, const float* __restrict__ tok, const float* __restrict__ pos,
    const float* __restrict__ g, const float* __restrict__ bta,
    const u16* __restrict__ WqkvT0,
    const float* __restrict__ bq, const float* __restrict__ bk, const float* __restrict__ bv,
    float* __restrict__ x, u16* __restrict__ qkv)
{
    __shared__ u16 Bs[2][256*64];
    __shared__ u16 hS[16][264];

    int tid = threadIdx.x;
    int lane = tid & 63, w = tid >> 6;
    int lr = lane & 15, lg = lane >> 4;
    int bid = xcd_swizzle(blockIdx.x, 256);
    int row0 = bid * 16;

    {
        int grow = tid >> 4;
        int gcol = (tid & 15) * 16;
        int n = row0 + grow;
        int t = n & (T_ - 1);
        int id = idx[n];
        float vv[16];
        #pragma unroll
        for (int i = 0; i < 4; i++) {
            float4 a = *(const float4*)(tok + (size_t)id * D_ + gcol + i * 4);
            float4 b = *(const float4*)(pos + (size_t)t * D_ + gcol + i * 4);
            vv[i*4+0] = a.x + b.x; vv[i*4+1] = a.y + b.y;
            vv[i*4+2] = a.z + b.z; vv[i*4+3] = a.w + b.w;
        }
        float s = 0.f, q = 0.f;
        #pragma unroll
        for (int i = 0; i < 16; i++) { s += vv[i]; q += vv[i]*vv[i]; }
        #pragma unroll
        for (int o = 1; o <= 8; o <<= 1) { s += __shfl_xor(s, o); q += __shfl_xor(q, o); }
        float mu = s * (1.0f / D_);
        float var = q * (1.0f / D_) - mu * mu;
        float ri = rsqrtf(var + 1e-5f);
        #pragma unroll
        for (int i = 0; i < 16; i++) {
            x[(size_t)n * D_ + gcol + i] = vv[i];
            hS[grow][gcol + i] = f2bf((vv[i] - mu) * ri * g[gcol + i] + bta[gcol + i]);
        }
    }

    auto stageQ = [&](int buf, int u) {
        const u16* BT = WqkvT0 + (size_t)(u >> 2) * 65536;
        int k0 = (u & 3) * 64;
        #pragma unroll
        for (int i = 0; i < 8; i++) {
            int o16 = tid + i * 256;
            int r = o16 >> 3;
            int sw = ((o16 & 7) << 4) ^ ((r & 7) << 4);
            GLOAD16(BT + (size_t)r * 256 + k0 + (sw >> 1), &Bs[buf][o16 * 8]);
        }
    };
    auto afH = [&](int t, int ks) -> bf16x8 {
        return *(const bf16x8*)(&hS[lr][(t * 128 + ks * 64 + lg * 16) >> 1]);
    };
    auto bfr = [&](int buf, int ni, int ks) -> bf16x8 {
        int rr = w * 64 + ni * 16 + lr;
        return *(const bf16x8*)(&Bs[buf][rr * 64 + (((ks * 64 + lg * 16) ^ ((rr & 7) << 4)) >> 1)]);
    };

    stageQ(0, 0);
    f32x4 acc[4] = {};
    for (int u = 0; u < 12; u++) {
        BAR_A();
        if (u + 1 < 12) { stageQ((u + 1) & 1, u + 1); WAITB(8); }
        else            { WAITB(0); }
        int t = u & 3;
        #pragma unroll
        for (int ks = 0; ks < 2; ks++) {
            bf16x8 a = afH(t, ks);
            __builtin_amdgcn_s_setprio(1);
            #pragma unroll
            for (int ni = 0; ni < 4; ni++)
                acc[ni] = __builtin_amdgcn_mfma_f32_16x16x32_bf16(a, bfr(u & 1, ni, ks), acc[ni], 0, 0, 0);
            __builtin_amdgcn_s_setprio(0);
        }
        if (t == 3) {
            int sel = u >> 2;
            const float* bp = sel == 0 ? bq : sel == 1 ? bk : bv;
            #pragma unroll
            for (int ni = 0; ni < 4; ni++) {
                #pragma unroll
                for (int j = 0; j < 4; j++) {
                    int row = row0 + lg * 4 + j;
                    int cc = w * 64 + ni * 16 + lr;
                    float v = acc[ni][j] + bp[cc];
                    int bb = row >> 11, tt = row & (T_ - 1);
                    int hh = cc >> 6, dh = cc & 63;
                    qkv[(size_t)sel * NTOK * D_ +
                        ((((size_t)bb * H_ + hh) * T_) + tt) * DH_ + dh] = f2bf(v);
                }
                acc[ni] = (f32x4){0.f, 0.f, 0.f, 0.f};
            }
        }
    }
}

// ================= Wo + residual + LN2: 256 blocks x 256t, 16 rows/block ==========
__global__ __launch_bounds__(256) void wo_ln_kernel(
    const u16* __restrict__ ybuf, const u16* __restrict__ WoT, const float* __restrict__ bo,
    const float* __restrict__ ln2g, const float* __restrict__ ln2b,
    float* __restrict__ x, u16* __restrict__ hbuf)
{
    __shared__ u16 As[2][16*64];
    __shared__ u16 Bs[2][256*64];
    __shared__ float sred[4][16], qred[4][16];

    int tid = threadIdx.x;
    int lane = tid & 63, w = tid >> 6;
    int lr = lane & 15, lg = lane >> 4;
    int bid = xcd_swizzle(blockIdx.x, 256);
    int row0 = bid * 16;

    // T14: hoist residual x reads before the K-loop (latency hidden under MFMA)
    float xv[4][4];
    #pragma unroll
    for (int ni = 0; ni < 4; ni++)
        #pragma unroll
        for (int j = 0; j < 4; j++)
            xv[ni][j] = x[(size_t)(row0 + lg * 4 + j) * D_ + w * 64 + ni * 16 + lr];

    auto stage = [&](int buf, int k0) {
        #pragma unroll
        for (int i = 0; i < 8; i++) {
            int o16 = tid + i * 256;
            int r = o16 >> 3;
            int sw = ((o16 & 7) << 4) ^ ((r & 7) << 4);
            GLOAD16(WoT + (size_t)r * 256 + k0 + (sw >> 1), &Bs[buf][o16 * 8]);
        }
        if (tid < 128) {
            int r = tid >> 3;
            int sw = ((tid & 7) << 4) ^ ((r & 7) << 4);
            GLOAD16(ybuf + (size_t)(row0 + r) * 256 + k0 + (sw >> 1), &As[buf][tid * 8]);
        }
    };
    auto afA = [&](int buf, int ks) -> bf16x8 {
        return *(const bf16x8*)(&As[buf][lr * 64 + (((ks * 64 + lg * 16) ^ ((lr & 7) << 4)) >> 1)]);
    };
    auto bfr = [&](int buf, int ni, int ks) -> bf16x8 {
        int rr = w * 64 + ni * 16 + lr;
        return *(const bf16x8*)(&Bs[buf][rr * 64 + (((ks * 64 + lg * 16) ^ ((rr & 7) << 4)) >> 1)]);
    };

    stage(0, 0);
    f32x4 acc[4] = {};
    for (int t = 0; t < 4; t++) {
        BAR_A();
        if (t + 1 < 4) { stage((t + 1) & 1, (t + 1) * 64); WAITB(8); }
        else           { WAITB(0); }
        #pragma unroll
        for (int ks = 0; ks < 2; ks++) {
            bf16x8 a = afA(t & 1, ks);
            __builtin_amdgcn_s_setprio(1);
            #pragma unroll
            for (int ni = 0; ni < 4; ni++)
                acc[ni] = __builtin_amdgcn_mfma_f32_16x16x32_bf16(a, bfr(t & 1, ni, ks), acc[ni], 0, 0, 0);
            __builtin_amdgcn_s_setprio(0);
        }
    }

    float vals[4][4];
    float rs[4] = {0,0,0,0}, rq[4] = {0,0,0,0};
    #pragma unroll
    for (int ni = 0; ni < 4; ni++)
        #pragma unroll
        for (int j = 0; j < 4; j++) {
            int row = row0 + lg * 4 + j;
            int col = w * 64 + ni * 16 + lr;
            float v = acc[ni][j] + bo[col] + xv[ni][j];
            x[(size_t)row * D_ + col] = v;
            vals[ni][j] = v;
            rs[j] += v; rq[j] += v * v;
        }
    #pragma unroll
    for (int j = 0; j < 4; j++)
        #pragma unroll
        for (int o = 1; o <= 8; o <<= 1) { rs[j] += __shfl_xor(rs[j], o); rq[j] += __shfl_xor(rq[j], o); }
    if (lr == 0)
        #pragma unroll
        for (int j = 0; j < 4; j++) { sred[w][lg*4 + j] = rs[j]; qred[w][lg*4 + j] = rq[j]; }
    __syncthreads();
    #pragma unroll
    for (int j = 0; j < 4; j++) {
        int r = lg * 4 + j;
        float mu = (sred[0][r] + sred[1][r] + sred[2][r] + sred[3][r]) * (1.0f / D_);
        float var = (qred[0][r] + qred[1][r] + qred[2][r] + qred[3][r]) * (1.0f / D_) - mu * mu;
        float ri = rsqrtf(var + 1e-5f);
        int row = row0 + r;
        #pragma unroll
        for (int ni = 0; ni < 4; ni++) {
            int col = w * 64 + ni * 16 + lr;
            hbuf[(size_t)row * D_ + col] = f2bf((vals[ni][j] - mu) * ri * ln2g[col] + ln2b[col]);
        }
    }
}

// ================= FF1 + GELU: 64x64 tiles, 1024 blocks, triple-buffered 1-barrier ======
__global__ __launch_bounds__(256) void ff1_kernel(
    const u16* __restrict__ A, const u16* __restrict__ BT,
    const float* __restrict__ bias, u16* __restrict__ C)
{
    __shared__ u16 As[3][64*64];
    __shared__ u16 Bs[3][64*64];
    int tid = threadIdx.x;
    int lane = tid & 63, w = tid >> 6;
    int lr = lane & 15, lg = lane >> 4;
    int wm = w >> 1, wn = w & 1;

    int gx = gridDim.x;
    int nwg = gx * gridDim.y;
    int orig = blockIdx.y * gx + blockIdx.x;
    int bid = xcd_swizzle(orig, nwg);
    int row0 = (bid / gx) * 64, col0 = (bid % gx) * 64;

    auto stage = [&](int buf, int k0) {
        #pragma unroll
        for (int i = 0; i < 2; i++) {
            int o16 = tid + i * 256;
            int r = o16 >> 3;
            int sw = ((o16 & 7) << 4) ^ ((r & 7) << 4);
            GLOAD16(A + (size_t)(row0 + r) * 256 + k0 + (sw >> 1), &As[buf][o16 * 8]);
            GLOAD16(BT + (size_t)(col0 + r) * 256 + k0 + (sw >> 1), &Bs[buf][o16 * 8]);
        }
    };

    f32x4 acc[2][2] = {};
    auto compute = [&](int buf) {
        #pragma unroll
        for (int ks = 0; ks < 2; ks++) {
            bf16x8 af[2], bfv[2];
            #pragma unroll
            for (int mi = 0; mi < 2; mi++) {
                int rr = wm * 32 + mi * 16 + lr;
                af[mi] = *(const bf16x8*)(&As[buf][rr * 64 + (((ks * 64 + lg * 16) ^ ((rr & 7) << 4)) >> 1)]);
            }
            #pragma unroll
            for (int ni = 0; ni < 2; ni++) {
                int rr = wn * 32 + ni * 16 + lr;
                bfv[ni] = *(const bf16x8*)(&Bs[buf][rr * 64 + (((ks * 64 + lg * 16) ^ ((rr & 7) << 4)) >> 1)]);
            }
            __builtin_amdgcn_s_setprio(1);
            #pragma unroll
            for (int mi = 0; mi < 2; mi++)
                #pragma unroll
                for (int ni = 0; ni < 2; ni++)
                    acc[mi][ni] = __builtin_amdgcn_mfma_f32_16x16x32_bf16(af[mi], bfv[ni], acc[mi][ni], 0, 0, 0);
            __builtin_amdgcn_s_setprio(0);
        }
    };

    // 3-buffer single-barrier pipeline: wait(stage t) -> barrier -> issue(t+2) -> compute(t)
    stage(0, 0); stage(1, 64);
    asm volatile("s_waitcnt vmcnt(4) lgkmcnt(0)" ::: "memory");
    asm volatile("s_barrier" ::: "memory");
    stage(2, 128);
    compute(0);
    asm volatile("s_waitcnt vmcnt(4) lgkmcnt(0)" ::: "memory");
    asm volatile("s_barrier" ::: "memory");
    stage(0, 192);
    compute(1);
    asm volatile("s_waitcnt vmcnt(4) lgkmcnt(0)" ::: "memory");
    asm volatile("s_barrier" ::: "memory");
    compute(2);
    asm volatile("s_waitcnt vmcnt(0) lgkmcnt(0)" ::: "memory");
    asm volatile("s_barrier" ::: "memory");
    compute(0);

    #pragma unroll
    for (int mi = 0; mi < 2; mi++)
        #pragma unroll
        for (int ni = 0; ni < 2; ni++)
            #pragma unroll
            for (int j = 0; j < 4; j++) {
                int row = row0 + wm * 32 + mi * 16 + lg * 4 + j;
                int col = col0 + wn * 32 + ni * 16 + lr;
                float v = acc[mi][ni][j] + bias[col];
                v = 0.5f * v * (1.0f + erff(v * 0.70710678118f));
                C[(size_t)row * DF_ + col] = f2bf(v);
            }
}

// ================= FF2 + residual + LN(next) + QKV(next): 256 blocks, 16 rows =========
template<bool LAST>
__global__ __launch_bounds__(256) void ff2qkv_kernel(
    const u16* __restrict__ ff, const u16* __restrict__ W2T, const float* __restrict__ b2,
    const float* __restrict__ lng, const float* __restrict__ lnb,
    const u16* __restrict__ WqkvT,
    const float* __restrict__ bq, const float* __restrict__ bk, const float* __restrict__ bv,
    float* __restrict__ x, u16* __restrict__ hout, u16* __restrict__ qkv)
{
    __shared__ u16 As[2][16*64];
    __shared__ u16 Bs[2][256*64];
    __shared__ u16 hS[16][264];
    __shared__ float sred[4][16], qred[4][16];

    int tid = threadIdx.x;
    int lane = tid & 63, w = tid >> 6;
    int lr = lane & 15, lg = lane >> 4;
    int bid = xcd_swizzle(blockIdx.x, 256);
    int row0 = bid * 16;

    // T14: hoist residual x reads
    float xv[4][4];
    #pragma unroll
    for (int ni = 0; ni < 4; ni++)
        #pragma unroll
        for (int j = 0; j < 4; j++)
            xv[ni][j] = x[(size_t)(row0 + lg * 4 + j) * D_ + w * 64 + ni * 16 + lr];

    auto stageB = [&](int buf, const u16* BT, int K, int k0) {
        #pragma unroll
        for (int i = 0; i < 8; i++) {
            int o16 = tid + i * 256;
            int r = o16 >> 3;
            int sw = ((o16 & 7) << 4) ^ ((r & 7) << 4);
            GLOAD16(BT + (size_t)r * K + k0 + (sw >> 1), &Bs[buf][o16 * 8]);
        }
    };
    auto stageA = [&](int buf, int k0) {
        if (tid < 128) {
            int r = tid >> 3;
            int sw = ((tid & 7) << 4) ^ ((r & 7) << 4);
            GLOAD16(ff + (size_t)(row0 + r) * DF_ + k0 + (sw >> 1), &As[buf][tid * 8]);
        }
    };
    auto prefetch = [&](int u) {
        if (u < 16) { stageA(u & 1, u * 64); stageB(u & 1, W2T, 1024, u * 64); }
        else if (!LAST && u < 28) {
            int v = u - 16;
            stageB(u & 1, WqkvT + (size_t)(v >> 2) * 65536, 256, (v & 3) * 64);
        }
    };
    auto afA = [&](int buf, int ks) -> bf16x8 {
        return *(const bf16x8*)(&As[buf][lr * 64 + (((ks * 64 + lg * 16) ^ ((lr & 7) << 4)) >> 1)]);
    };
    auto afH = [&](int t, int ks) -> bf16x8 {
        return *(const bf16x8*)(&hS[lr][(t * 128 + ks * 64 + lg * 16) >> 1]);
    };
    auto bfr = [&](int buf, int ni, int ks) -> bf16x8 {
        int rr = w * 64 + ni * 16 + lr;
        return *(const bf16x8*)(&Bs[buf][rr * 64 + (((ks * 64 + lg * 16) ^ ((rr & 7) << 4)) >> 1)]);
    };

    prefetch(0);
    f32x4 acc[4] = {};
    for (int u = 0; u < 16; u++) {
        BAR_A();
        prefetch(u + 1);
        WAITB(8);
        #pragma unroll
        for (int ks = 0; ks < 2; ks++) {
            bf16x8 a = afA(u & 1, ks);
            __builtin_amdgcn_s_setprio(1);
            #pragma unroll
            for (int ni = 0; ni < 4; ni++)
                acc[ni] = __builtin_amdgcn_mfma_f32_16x16x32_bf16(a, bfr(u & 1, ni, ks), acc[ni], 0, 0, 0);
            __builtin_amdgcn_s_setprio(0);
        }
    }

    {
        float vals[4][4];
        float rs[4] = {0,0,0,0}, rq[4] = {0,0,0,0};
        #pragma unroll
        for (int ni = 0; ni < 4; ni++)
            #pragma unroll
            for (int j = 0; j < 4; j++) {
                int row = row0 + lg * 4 + j;
                int col = w * 64 + ni * 16 + lr;
                float v = acc[ni][j] + b2[col] + xv[ni][j];
                x[(size_t)row * D_ + col] = v;
                vals[ni][j] = v;
                rs[j] += v; rq[j] += v * v;
            }
        #pragma unroll
        for (int j = 0; j < 4; j++)
            #pragma unroll
            for (int o = 1; o <= 8; o <<= 1) { rs[j] += __shfl_xor(rs[j], o); rq[j] += __shfl_xor(rq[j], o); }
        if (lr == 0)
            #pragma unroll
            for (int j = 0; j < 4; j++) { sred[w][lg*4 + j] = rs[j]; qred[w][lg*4 + j] = rq[j]; }
        __syncthreads();
        #pragma unroll
        for (int j = 0; j < 4; j++) {
            int r = lg * 4 + j;
            float mu = (sred[0][r] + sred[1][r] + sred[2][r] + sred[3][r]) * (1.0f / D_);
            float var = (qred[0][r] + qred[1][r] + qred[2][r] + qred[3][r]) * (1.0f / D_) - mu * mu;
            float ri = rsqrtf(var + 1e-5f);
            #pragma unroll
            for (int ni = 0; ni < 4; ni++) {
                int col = w * 64 + ni * 16 + lr;
                float hv = (vals[ni][j] - mu) * ri * lng[col] + lnb[col];
                if (LAST) hout[(size_t)(row0 + r) * D_ + col] = f2bf(hv);
                else      hS[r][col] = f2bf(hv);
            }
        }
    }

    if constexpr (!LAST) {
        __syncthreads();
        f32x4 accT[4] = {};
        for (int v = 0; v < 12; v++) {
            BAR_A();
            if (v + 1 < 12) { prefetch(16 + v + 1); WAITB(8); }
            else            { WAITB(0); }
            int t = v & 3;
            #pragma unroll
            for (int ks = 0; ks < 2; ks++) {
                bf16x8 a = afH(t, ks);
                __builtin_amdgcn_s_setprio(1);
                #pragma unroll
                for (int ni = 0; ni < 4; ni++)
                    accT[ni] = __builtin_amdgcn_mfma_f32_16x16x32_bf16(a, bfr(v & 1, ni, ks), accT[ni], 0, 0, 0);
                __builtin_amdgcn_s_setprio(0);
            }
            if (t == 3) {
                int sel = v >> 2;
                const float* bp = sel == 0 ? bq : sel == 1 ? bk : bv;
                #pragma unroll
                for (int ni = 0; ni < 4; ni++) {
                    #pragma unroll
                    for (int j = 0; j < 4; j++) {
                        int row = row0 + lg * 4 + j;
                        int cc = w * 64 + ni * 16 + lr;
                        float val = accT[ni][j] + bp[cc];
                        int bb = row >> 11, tt = row & (T_ - 1);
                        int hh = cc >> 6, dh = cc & 63;
                        qkv[(size_t)sel * NTOK * D_ +
                            ((((size_t)bb * H_ + hh) * T_) + tt) * DH_ + dh] = f2bf(val);
                    }
                    accT[ni] = (f32x4){0.f, 0.f, 0.f, 0.f};
                }
            }
        }
    }
}

// ================= attention: QBLK=32, key-parity split over wave pairs, balanced =====
__global__ __launch_bounds__(256) void attn_kernel(
    const u16* __restrict__ q, const u16* __restrict__ k,
    const u16* __restrict__ v, u16* __restrict__ y)
{
    int linear = blockIdx.y * gridDim.x + blockIdx.x;   // 0..511
    int half = linear >> 8, rem = linear & 255;
    int qt_raw = rem & 63;
    int qt = half ? 63 - qt_raw : qt_raw;
    int bh = (rem >> 6) + half * 4;
    int bidx = bh >> 2, h = bh & 3;
    const u16* qp = q + (size_t)bh * T_ * DH_;
    const u16* kp = k + (size_t)bh * T_ * DH_;
    const u16* vp = v + (size_t)bh * T_ * DH_;

    int nch = (qt + 2) >> 1;

    __shared__ u16 Qs[32*64];
    __shared__ u16 Ks[2][2][64*64];
    __shared__ u16 VT[2][64*72];
    __shared__ u16 Ps[4][16*72];

    int tid = threadIdx.x;
    int lane = tid & 63, w = tid >> 6;
    int lr = lane & 15, lg = lane >> 4;
    int p = w >> 1;
    int rh = w & 1;
    int cnt0 = (nch + 1) >> 1, cnt1 = nch >> 1;
    int mycnt = p ? cnt1 : cnt0;
    int maxit = cnt0;

    int pp = tid >> 7;
    int ppcnt = pp ? cnt1 : cnt0;
    int vkey = tid & 63;
    int vdh0 = ((tid >> 6) & 1) * 8;

    {
        int o16 = tid, r = o16 >> 3;
        int sw = ((o16 & 7) << 4) ^ ((r & 7) << 4);
        GLOAD16(qp + (size_t)(qt * 32 + r) * DH_ + (sw >> 1), &Qs[o16 * 8]);
    }
    #pragma unroll
    for (int pr = 0; pr < 2; pr++) {
        int c = min(pr, nch - 1);
        #pragma unroll
        for (int i = 0; i < 2; i++) {
            int o16 = tid + i * 256, r = o16 >> 3;
            int sw = ((o16 & 7) << 4) ^ ((r & 7) << 4);
            GLOAD16(kp + (size_t)(c * 64 + r) * DH_ + (sw >> 1), &Ks[0][pr][o16 * 8]);
        }
    }
    bf16x8 vr[4];
    {
        int c = min(pp, nch - 1);
        #pragma unroll
        for (int g = 0; g < 4; g++)
            vr[g] = *(const bf16x8*)(vp + (size_t)(c * 64 + vkey) * DH_ + vdh0 + g * 16);
    }
    __syncthreads();
    #pragma unroll
    for (int g = 0; g < 4; g++)
        #pragma unroll
        for (int e = 0; e < 8; e++)
            VT[pp][(vdh0 + g * 16 + e) * 72 + vkey] = (u16)vr[g][e];
    bf16x8 qa[2];
    #pragma unroll
    for (int ks = 0; ks < 2; ks++) {
        int rr = rh * 16 + lr;
        qa[ks] = *(const bf16x8*)(Qs + rr * 64 + (((ks * 64 + lg * 16) ^ ((rr & 7) << 4)) >> 1));
    }
    __syncthreads();

    float m[4], lden[4];
    f32x4 o[4] = {};
    #pragma unroll
    for (int j = 0; j < 4; j++) { m[j] = -1e30f; lden[j] = 0.0f; }

    for (int it = 0; it < maxit; it++) {
        int cur = it & 1;
        if (it + 1 < maxit) {
            #pragma unroll
            for (int pr = 0; pr < 2; pr++) {
                int c = min(2 * (it + 1) + pr, nch - 1);
                #pragma unroll
                for (int i = 0; i < 2; i++) {
                    int o16 = tid + i * 256, r = o16 >> 3;
                    int sw = ((o16 & 7) << 4) ^ ((r & 7) << 4);
                    GLOAD16(kp + (size_t)(c * 64 + r) * DH_ + (sw >> 1), &Ks[cur ^ 1][pr][o16 * 8]);
                }
            }
        }
        bool vnext = (it + 1 < ppcnt);
        if (vnext) {
            int c = 2 * (it + 1) + pp;
            #pragma unroll
            for (int g = 0; g < 4; g++)
                vr[g] = *(const bf16x8*)(vp + (size_t)(c * 64 + vkey) * DH_ + vdh0 + g * 16);
        }

        bool act = (it < mycnt);
        if (act) {
            int myc = 2 * it + p;
            f32x4 sc[4];
            #pragma unroll
            for (int ct = 0; ct < 4; ct++) {
                f32x4 s = {};
                __builtin_amdgcn_s_setprio(1);
                #pragma unroll
                for (int ks = 0; ks < 2; ks++) {
                    int rr = ct * 16 + lr;
                    bf16x8 kb = *(const bf16x8*)(&Ks[cur][p][rr * 64 + (((ks * 64 + lg * 16) ^ ((rr & 7) << 4)) >> 1)]);
                    s = __builtin_amdgcn_mfma_f32_16x16x32_bf16(qa[ks], kb, s, 0, 0, 0);
                }
                __builtin_amdgcn_s_setprio(0);
                sc[ct] = s;
            }
            float mloc[4];
            #pragma unroll
            for (int j = 0; j < 4; j++) mloc[j] = -1e30f;
            #pragma unroll
            for (int ct = 0; ct < 4; ct++)
                #pragma unroll
                for (int j = 0; j < 4; j++) {
                    float s = sc[ct][j] * 0.125f;
                    int key = myc * 64 + ct * 16 + lr;
                    int qrow = qt * 32 + rh * 16 + lg * 4 + j;
                    if (key > qrow) s = -1e30f;
                    sc[ct][j] = s;
                    mloc[j] = fmaxf(mloc[j], s);
                }
            #pragma unroll
            for (int j = 0; j < 4; j++) {
                mloc[j] = fmaxf(mloc[j], __shfl_xor(mloc[j], 1));
                mloc[j] = fmaxf(mloc[j], __shfl_xor(mloc[j], 2));
                mloc[j] = fmaxf(mloc[j], __shfl_xor(mloc[j], 4));
                mloc[j] = fmaxf(mloc[j], __shfl_xor(mloc[j], 8));
            }
            float f[4], rs[4];
            #pragma unroll
            for (int j = 0; j < 4; j++) {
                float nm = fmaxf(m[j], mloc[j]);
                f[j] = __expf(m[j] - nm);
                m[j] = nm;
                rs[j] = 0.0f;
            }
            #pragma unroll
            for (int ct = 0; ct < 4; ct++)
                #pragma unroll
                for (int j = 0; j < 4; j++) {
                    float pv = __expf(sc[ct][j] - m[j]);
                    rs[j] += pv;
                    Ps[w][(lg * 4 + j) * 72 + ct * 16 + lr] = f2bf(pv);
                }
            #pragma unroll
            for (int j = 0; j < 4; j++) {
                rs[j] += __shfl_xor(rs[j], 1);
                rs[j] += __shfl_xor(rs[j], 2);
                rs[j] += __shfl_xor(rs[j], 4);
                rs[j] += __shfl_xor(rs[j], 8);
                lden[j] = lden[j] * f[j] + rs[j];
            }
            #pragma unroll
            for (int dt = 0; dt < 4; dt++)
                #pragma unroll
                for (int j = 0; j < 4; j++)
                    o[dt][j] *= f[j];
            #pragma unroll
            for (int ks = 0; ks < 2; ks++) {
                bf16x8 pa = *(const bf16x8*)(&Ps[w][lr * 72 + ks * 32 + lg * 8]);
                __builtin_amdgcn_s_setprio(1);
                #pragma unroll
                for (int dt = 0; dt < 4; dt++) {
                    bf16x8 vb = *(const bf16x8*)(&VT[p][(dt * 16 + lr) * 72 + ks * 32 + lg * 8]);
                    o[dt] = __builtin_amdgcn_mfma_f32_16x16x32_bf16(pa, vb, o[dt], 0, 0, 0);
                }
                __builtin_amdgcn_s_setprio(0);
            }
        }
        __syncthreads();
        if (vnext) {
            #pragma unroll
            for (int g = 0; g < 4; g++)
                #pragma unroll
                for (int e = 0; e < 8; e++)
                    VT[pp][(vdh0 + g * 16 + e) * 72 + vkey] = (u16)vr[g][e];
        }
        __syncthreads();
    }

    float* mg = (float*)&Ks[0][0][0];
    if (p == 1) {
        int base = (rh * 64 + lane) * 24;
        #pragma unroll
        for (int dt = 0; dt < 4; dt++)
            #pragma unroll
            for (int j = 0; j < 4; j++)
                mg[base + dt * 4 + j] = o[dt][j];
        #pragma unroll
        for (int j = 0; j < 4; j++) { mg[base + 16 + j] = m[j]; mg[base + 20 + j] = lden[j]; }
    }
    __syncthreads();
    if (p == 0) {
        int base = (rh * 64 + lane) * 24;
        #pragma unroll
        for (int j = 0; j < 4; j++) {
            float m1 = mg[base + 16 + j];
            float l1 = mg[base + 20 + j];
            float mf = fmaxf(m[j], m1);
            float e0 = __expf(m[j] - mf), e1 = __expf(m1 - mf);
            float inv = 1.0f / (lden[j] * e0 + l1 * e1);
            int qrow = qt * 32 + rh * 16 + lg * 4 + j;
            size_t ybase = ((size_t)(bidx * T_ + qrow)) * D_ + h * DH_;
            #pragma unroll
            for (int dt = 0; dt < 4; dt++) {
                float of = (o[dt][j] * e0 + mg[base + dt * 4 + j] * e1) * inv;
                y[ybase + dt * 16 + lr] = f2bf(of);
            }
        }
    }
}

// ================= head GEMM: BK=32, 3 blocks/CU, LDS-transposed f32x4 nt stores ======
__global__ __launch_bounds__(256, 3) void head_gemm(
    const u16* __restrict__ A, const u16* __restrict__ BT,
    const float* __restrict__ bias, float* __restrict__ C,
    int M, int N, int K)
{
    __shared__ u16 smem[16384];   // 32 KB: As[2][4096] | Bs[2][4096]; reused as f32[128][64] x2 passes
    u16* As = smem;
    u16* Bs = smem + 8192;
    int tid = threadIdx.x;
    int lane = tid & 63, w = tid >> 6;
    int lr = lane & 15, lg = lane >> 4;
    int wm = w >> 1, wn = w & 1;

    int orig = blockIdx.y * gridDim.x + blockIdx.x;   // 8000 blocks
    int bid = xcd_swizzle(orig, 8000);
    int col0 = (bid >> 5) * 128;
    int row0 = (bid & 31) * 128;

    f32x4 acc[4][4] = {};

    // BK=32: rows are 64 B; swizzle slot (r&3)<<4
    auto stage = [&](int buf, int k0) {
        #pragma unroll
        for (int i = 0; i < 2; i++) {
            int o16 = tid + i * 256;          // 0..511
            int r = o16 >> 2;                 // 4 chunks per 64 B row
            int sw = ((o16 & 3) << 4) ^ ((r & 3) << 4);
            GLOAD16(A + (size_t)(row0 + r) * K + k0 + (sw >> 1), &As[buf * 4096 + o16 * 8]);
            GLOAD16(BT + (size_t)(col0 + r) * K + k0 + (sw >> 1), &Bs[buf * 4096 + o16 * 8]);
        }
    };

    stage(0, 0);
    int nk = K >> 5;                          // 8 steps
    for (int t = 0; t < nk; t++) {
        int cur = t & 1;
        BAR_A();
        if (t + 1 < nk) { stage(cur ^ 1, (t + 1) << 5); WAITB(4); }
        else            { WAITB(0); }
        bf16x8 af[4], bfr[4];
        #pragma unroll
        for (int mi = 0; mi < 4; mi++) {
            int rr = wm * 64 + mi * 16 + lr;
            af[mi] = *(const bf16x8*)(&As[cur * 4096 + rr * 32 + (((lg * 16) ^ ((rr & 3) << 4)) >> 1)]);
        }
        #pragma unroll
        for (int ni = 0; ni < 4; ni++) {
            int rr = wn * 64 + ni * 16 + lr;
            bfr[ni] = *(const bf16x8*)(&Bs[cur * 4096 + rr * 32 + (((lg * 16) ^ ((rr & 3) << 4)) >> 1)]);
        }
        __builtin_amdgcn_s_setprio(1);
        #pragma unroll
        for (int mi = 0; mi < 4; mi++)
            #pragma unroll
            for (int ni = 0; ni < 4; ni++)
                acc[mi][ni] = __builtin_amdgcn_mfma_f32_16x16x32_bf16(af[mi], bfr[ni], acc[mi][ni], 0, 0, 0);
        __builtin_amdgcn_s_setprio(0);
    }

    // epilogue: two half-tile passes through 32 KB LDS, coalesced f32x4 nt stores
    float* tS = (float*)smem;     // [128][64] f32 per pass, chunk-swizzled
    #pragma unroll
    for (int half = 0; half < 2; half++) {    // half = wn selector: cols [half*64, half*64+64)
        __syncthreads();
        if (wn == half) {
            #pragma unroll
            for (int mi = 0; mi < 4; mi++)
                #pragma unroll
                for (int ni = 0; ni < 4; ni++)
                    #pragma unroll
                    for (int j = 0; j < 4; j++) {
                        int rl = wm * 64 + mi * 16 + lg * 4 + j;
                        int cl = ni * 16 + lr;                       // 0..63 within half
                        int ch = (cl >> 2) ^ (rl & 3);               // 16 chunks of 4 f32
                        tS[rl * 64 + (ch & 15) * 4 + (cl & 3)] = acc[mi][ni][j] + bias[col0 + half * 64 + cl];
                    }
        }
        __syncthreads();
        int cc = tid & 15, r0l = (tid >> 4) * 8;
        #pragma unroll
        for (int i = 0; i < 8; i++) {
            int rl = r0l + i;
            int sch = (cc ^ (rl & 3)) & 15;
            f32x4 v4 = *(const f32x4*)&tS[rl * 64 + sch * 4];
            __builtin_nontemporal_store(v4, (f32x4*)&C[(size_t)(row0 + rl) * N + col0 + half * 64 + cc * 4]);
        }
    }
}

// ================= host launch =================
extern "C" void kernel_launch(void* const* d_in, const int* in_sizes, int n_in,
                              void* d_out, int out_size, void* d_ws, size_t ws_size,
                              hipStream_t stream)
{
    const int*   idx  = (const int*)d_in[0];
    const float* tok  = (const float*)d_in[1];
    const float* pos  = (const float*)d_in[2];
    const float* Wq   = (const float*)d_in[3];
    const float* bq   = (const float*)d_in[4];
    const float* Wk   = (const float*)d_in[5];
    const float* bk   = (const float*)d_in[6];
    const float* Wv   = (const float*)d_in[7];
    const float* bv   = (const float*)d_in[8];
    const float* Wo   = (const float*)d_in[9];
    const float* bo   = (const float*)d_in[10];
    const float* ln1g = (const float*)d_in[11];
    const float* ln1b = (const float*)d_in[12];
    const float* W1   = (const float*)d_in[13];
    const float* b1   = (const float*)d_in[14];
    const float* W2   = (const float*)d_in[15];
    const float* b2   = (const float*)d_in[16];
    const float* ln2g = (const float*)d_in[17];
    const float* ln2b = (const float*)d_in[18];
    const float* lnfg = (const float*)d_in[19];
    const float* lnfb = (const float*)d_in[20];
    const float* hW   = (const float*)d_in[21];
    const float* hb   = (const float*)d_in[22];

    char* p = (char*)d_ws;
    float* x     = (float*)p;           p += (size_t)NTOK * D_ * 4;
    u16* hbuf    = (u16*)p;             p += (size_t)NTOK * D_ * 2;
    u16* qkvbuf  = (u16*)p;             p += (size_t)3 * NTOK * D_ * 2;
    u16* ybuf    = (u16*)p;             p += (size_t)NTOK * D_ * 2;
    u16* ff      = (u16*)p;             p += (size_t)NTOK * DF_ * 2;
    u16* WqkvT   = (u16*)p;             p += (size_t)L_ * 768 * D_ * 2;
    u16* WoT     = (u16*)p;             p += (size_t)L_ * D_ * D_ * 2;
    u16* W1T     = (u16*)p;             p += (size_t)L_ * D_ * DF_ * 2;
    u16* W2T     = (u16*)p;             p += (size_t)L_ * DF_ * D_ * 2;
    u16* hWT     = (u16*)p;             p += (size_t)V_ * D_ * 2;

    u16* qbuf = qkvbuf;
    u16* kbuf = qkvbuf + (size_t)NTOK * D_;
    u16* vbuf = qkvbuf + (size_t)2 * NTOK * D_;

    prep_kernel<<<5536, 256, 0, stream>>>(Wq, Wk, Wv, Wo, W1, W2, hW,
                                          WqkvT, WoT, W1T, W2T, hWT);

    embed_qkv_kernel<<<256, 256, 0, stream>>>(idx, tok, pos, ln1g, ln1b,
                                              WqkvT, bq, bk, bv, x, qkvbuf);

    dim3 gAttn(64, 8);                   // 512 balanced blocks
    dim3 gFF1(DF_ / 64, NTOK / 64);      // (16, 64)
    for (int l = 0; l < L_; l++) {
        attn_kernel<<<gAttn, 256, 0, stream>>>(qbuf, kbuf, vbuf, ybuf);
        wo_ln_kernel<<<256, 256, 0, stream>>>(ybuf, WoT + (size_t)l * 65536, bo + l * D_,
                                              ln2g + l * D_, ln2b + l * D_, x, hbuf);
        ff1_kernel<<<gFF1, 256, 0, stream>>>(hbuf, W1T + (size_t)l * 262144, b1 + l * DF_, ff);
        if (l < L_ - 1) {
            ff2qkv_kernel<false><<<256, 256, 0, stream>>>(
                ff, W2T + (size_t)l * 262144, b2 + l * D_,
                ln1g + (l + 1) * D_, ln1b + (l + 1) * D_,
                WqkvT + (size_t)(l + 1) * 196608,
                bq + (l + 1) * D_, bk + (l + 1) * D_, bv + (l + 1) * D_,
                x, nullptr, qkvbuf);
        } else {
            ff2qkv_kernel<true><<<256, 256, 0, stream>>>(
                ff, W2T + (size_t)l * 262144, b2 + l * D_,
                lnfg, lnfb,
                nullptr, nullptr, nullptr, nullptr,
                x, hbuf, nullptr);
        }
    }

    dim3 gHead(V_ / 128, NTOK / 128);    // (250, 32)
    head_gemm<<<gHead, 256, 0, stream>>>(hbuf, hWT, hb, (float*)d_out, NTOK, V_, D_);
}